// Round 1
// baseline (240.834 us; speedup 1.0000x reference)
//
#include <hip/hip_runtime.h>

// Problem constants
#define B_    8
#define CIN_  64
#define H_    128
#define W_    128
#define OC_   128
#define HO_   64
#define WO_   64
#define NPOS  (B_ * HO_ * WO_)   // 32768

// ws layout (float offsets)
#define XT_OFF   0            // x_t: (B,H,W,CIN) = 8*128*128*64 = 8388608 floats
#define G_OFF    8388608      // G:   (NPOS,128)  = 4194304 floats
#define M_OFF    12582912     // M:   64*64 = 4096 floats
#define WPOS_OFF 12587008     // wpos0[25] at +0, wpos1[25] at +32

// ---------------------------------------------------------------------------
// Kernel A: M = W_q^T W_k (64x64) and wpos (2x25 softmax over mixtures)
// grid = 17 blocks x 256
// ---------------------------------------------------------------------------
__global__ __launch_bounds__(256) void prep_kernel(
    const float* __restrict__ w_q, const float* __restrict__ w_k,
    const float* __restrict__ row_emb, const float* __restrict__ col_emb,
    const float* __restrict__ mix_emb, float* __restrict__ M,
    float* __restrict__ wpos) {
  if (blockIdx.x < 16) {
    int idx = blockIdx.x * 256 + threadIdx.x;  // 0..4095
    int a = idx >> 6;       // wave-uniform -> scalar loads for w_q
    int bb = idx & 63;      // coalesced for w_k
    float acc = 0.f;
    #pragma unroll 8
    for (int o = 0; o < 128; ++o)
      acc = fmaf(w_q[o * 64 + a], w_k[o * 64 + bb], acc);
    M[idx] = acc;  // M[a*64 + b] = sum_o w_q[o,a] * w_k[o,b]
  } else {
    int p = threadIdx.x;
    if (p < 25) {
      int i = p / 5, j = p % 5;
      float a0 = 0.f, a1 = 0.f;
      for (int c = 0; c < 128; ++c) {
        float rc = row_emb[c * 5 + i] + col_emb[c * 5 + j];
        a0 = fmaf(rc, mix_emb[c * 2 + 0], a0);
        a1 = fmaf(rc, mix_emb[c * 2 + 1], a1);
      }
      float mx = fmaxf(a0, a1);
      float e0 = __expf(a0 - mx), e1 = __expf(a1 - mx);
      float inv = 1.f / (e0 + e1);
      wpos[p] = e0 * inv;
      wpos[32 + p] = e1 * inv;
    }
  }
}

// ---------------------------------------------------------------------------
// Kernel T: transpose x (B,C,H,W) -> x_t (B,H,W,C). grid = B*H blocks x 256
// ---------------------------------------------------------------------------
__global__ __launch_bounds__(256) void transpose_kernel(
    const float* __restrict__ x, float* __restrict__ x_t) {
  __shared__ float tile[64][129];  // pad to kill bank conflicts
  int by = blockIdx.x;            // b*128 + y
  int b = by >> 7, y = by & 127;
  const float* xp = x + (size_t)b * (CIN_ * H_ * W_) + (size_t)y * W_;
  #pragma unroll
  for (int it = 0; it < 32; ++it) {
    int idx = threadIdx.x + it * 256;
    int c = idx >> 7, xw = idx & 127;
    tile[c][xw] = xp[(size_t)c * (H_ * W_) + xw];  // coalesced along xw
  }
  __syncthreads();
  float* xtp = x_t + ((size_t)b * (H_ * W_) + (size_t)y * W_) * CIN_;
  #pragma unroll
  for (int it = 0; it < 32; ++it) {
    int idx = threadIdx.x + it * 256;
    int xw = idx >> 6, c = idx & 63;
    xtp[idx] = tile[c][xw];  // contiguous store, conflict-free read
  }
}

// ---------------------------------------------------------------------------
// Kernel C: fused attention. One wave (64 lanes = channels) per output pos.
// grid = NPOS/4 blocks x 256 (4 waves/block, independent).
// ---------------------------------------------------------------------------
__global__ __launch_bounds__(256) void attn_kernel(
    const float* __restrict__ x_t, const float* __restrict__ M,
    const float* __restrict__ wpos, float* __restrict__ G) {
  int wave = threadIdx.x >> 6;
  int lane = threadIdx.x & 63;
  int pos = blockIdx.x * 4 + wave;   // 0..32767
  int b = pos >> 12;
  int ho = (pos >> 6) & 63;
  int wo = pos & 63;
  int y0 = 2 * ho, x0 = 2 * wo;

  const float* xb = x_t + (size_t)b * (H_ * W_ * CIN_);

  // q-pixel channel vector (coalesced 256B)
  float xq = xb[(size_t)(y0 * W_ + x0) * CIN_ + lane];

  // u[lane] = sum_a xq[a] * M[a*64 + lane]  (readlane broadcast + coalesced M)
  float u0 = 0.f, u1 = 0.f;
  #pragma unroll
  for (int a = 0; a < 64; a += 2) {
    float xa0 = __shfl(xq, a);
    float xa1 = __shfl(xq, a + 1);
    u0 = fmaf(xa0, M[a * 64 + lane], u0);
    u1 = fmaf(xa1, M[(a + 1) * 64 + lane], u1);
  }
  float u = u0 + u1;

  // load 25 tap vectors, per-lane partial scores
  float xv[25], s[25];
  #pragma unroll
  for (int p = 0; p < 25; ++p) {
    int i = p / 5, j = p % 5;
    int y = y0 - 2 + i, xw = x0 - 2 + j;
    bool valid = ((unsigned)y < (unsigned)H_) && ((unsigned)xw < (unsigned)W_);
    xv[p] = valid ? xb[(size_t)(y * W_ + xw) * CIN_ + lane] : 0.f;
    s[p] = u * xv[p];
  }

  // butterfly reduce all 25 scores across 64 lanes
  #pragma unroll
  for (int off = 32; off > 0; off >>= 1) {
    #pragma unroll
    for (int p = 0; p < 25; ++p) s[p] += __shfl_xor(s[p], off);
  }

  // softmax over 25 (redundant per lane; OOB taps correctly contribute exp(0))
  float m = s[0];
  #pragma unroll
  for (int p = 1; p < 25; ++p) m = fmaxf(m, s[p]);
  float Z = 0.f;
  #pragma unroll
  for (int p = 0; p < 25; ++p) { s[p] = __expf(s[p] - m); Z += s[p]; }
  float rZ = 1.f / Z;

  // g_m[lane] = sum_p attn_p * wpos[m,p] * xv[p]
  float g0 = 0.f, g1 = 0.f;
  #pragma unroll
  for (int p = 0; p < 25; ++p) {
    float ap = s[p] * rZ;
    g0 = fmaf(ap * wpos[p], xv[p], g0);
    g1 = fmaf(ap * wpos[32 + p], xv[p], g1);
  }
  G[(size_t)pos * 128 + lane] = g0;
  G[(size_t)pos * 128 + 64 + lane] = g1;
}

// ---------------------------------------------------------------------------
// Kernel D: out[c,pos] = w_v[2c]·g0(pos) + w_v[2c+1]·g1(pos)
// thread = position (coalesced G loads via float4, coalesced out stores,
// w_v indices wave-uniform -> scalar loads). grid = 512 (128 pos-blk x 4 cgrp)
// ---------------------------------------------------------------------------
__global__ __launch_bounds__(256) void out_kernel(
    const float* __restrict__ G, const float* __restrict__ w_v,
    float* __restrict__ out) {
  int pos_block = blockIdx.x >> 2;
  int cg = blockIdx.x & 3;            // channel group: 32 channels
  int pos = pos_block * 256 + threadIdx.x;

  float g[128];
  const float* Gp = G + (size_t)pos * 128;
  #pragma unroll
  for (int d = 0; d < 128; d += 4) {
    float4 t = *reinterpret_cast<const float4*>(Gp + d);
    g[d] = t.x; g[d + 1] = t.y; g[d + 2] = t.z; g[d + 3] = t.w;
  }

  int b = pos >> 12;
  int hw = pos & 4095;
  float* op = out + (size_t)b * (OC_ * HO_ * WO_) + hw;

  for (int c = cg * 32; c < cg * 32 + 32; ++c) {
    const float* wr = w_v + (size_t)(2 * c) * 64;  // rows 2c,2c+1 contiguous
    float a0 = 0.f, a1 = 0.f, a2 = 0.f, a3 = 0.f;
    #pragma unroll
    for (int d = 0; d < 128; d += 4) {
      a0 = fmaf(wr[d],     g[d],     a0);
      a1 = fmaf(wr[d + 1], g[d + 1], a1);
      a2 = fmaf(wr[d + 2], g[d + 2], a2);
      a3 = fmaf(wr[d + 3], g[d + 3], a3);
    }
    op[(size_t)c * (HO_ * WO_)] = (a0 + a1) + (a2 + a3);
  }
}

// ---------------------------------------------------------------------------
extern "C" void kernel_launch(void* const* d_in, const int* in_sizes, int n_in,
                              void* d_out, int out_size, void* d_ws, size_t ws_size,
                              hipStream_t stream) {
  const float* x       = (const float*)d_in[0];
  const float* w_q     = (const float*)d_in[1];
  const float* w_k     = (const float*)d_in[2];
  const float* w_v     = (const float*)d_in[3];
  const float* row_emb = (const float*)d_in[4];
  const float* col_emb = (const float*)d_in[5];
  const float* mix_emb = (const float*)d_in[6];
  float* out = (float*)d_out;

  float* ws   = (float*)d_ws;
  float* x_t  = ws + XT_OFF;
  float* G    = ws + G_OFF;
  float* M    = ws + M_OFF;
  float* wpos = ws + WPOS_OFF;

  prep_kernel<<<17, 256, 0, stream>>>(w_q, w_k, row_emb, col_emb, mix_emb, M, wpos);
  transpose_kernel<<<B_ * H_, 256, 0, stream>>>(x, x_t);
  attn_kernel<<<NPOS / 4, 256, 0, stream>>>(x_t, M, wpos, G);
  out_kernel<<<512, 256, 0, stream>>>(G, w_v, out);
}

// Round 2
// 161.178 us; speedup vs baseline: 1.4942x; 1.4942x over previous
//
#include <hip/hip_runtime.h>

// Problem constants
#define B_    8
#define CIN_  64
#define H_    128
#define W_    128
#define OC_   128
#define HO_   64
#define WO_   64
#define NPOS  (B_ * HO_ * WO_)   // 32768

// ws layout (float offsets)
#define XT_OFF   0            // x_t: (B,H,W,CIN) = 8*128*128*64 = 8388608 floats
#define G_OFF    8388608      // G:   (NPOS,128)  = 4194304 floats
#define M_OFF    12582912     // M:   64*64 = 4096 floats
#define WPOS_OFF 12587008     // wpos0[25] at +0, wpos1[25] at +32

// ---------------------------------------------------------------------------
// Kernel A: M = W_q^T W_k (64x64) and wpos (2x25 softmax over mixtures)
// grid = 17 blocks x 256
// ---------------------------------------------------------------------------
__global__ __launch_bounds__(256) void prep_kernel(
    const float* __restrict__ w_q, const float* __restrict__ w_k,
    const float* __restrict__ row_emb, const float* __restrict__ col_emb,
    const float* __restrict__ mix_emb, float* __restrict__ M,
    float* __restrict__ wpos) {
  if (blockIdx.x < 16) {
    int idx = blockIdx.x * 256 + threadIdx.x;  // 0..4095
    int a = idx >> 6;       // wave-uniform -> scalar loads for w_q
    int bb = idx & 63;      // coalesced for w_k
    float acc = 0.f;
    #pragma unroll 8
    for (int o = 0; o < 128; ++o)
      acc = fmaf(w_q[o * 64 + a], w_k[o * 64 + bb], acc);
    M[idx] = acc;  // M[a*64 + b] = sum_o w_q[o,a] * w_k[o,b]
  } else {
    int p = threadIdx.x;
    if (p < 25) {
      int i = p / 5, j = p % 5;
      float a0 = 0.f, a1 = 0.f;
      for (int c = 0; c < 128; ++c) {
        float rc = row_emb[c * 5 + i] + col_emb[c * 5 + j];
        a0 = fmaf(rc, mix_emb[c * 2 + 0], a0);
        a1 = fmaf(rc, mix_emb[c * 2 + 1], a1);
      }
      float mx = fmaxf(a0, a1);
      float e0 = __expf(a0 - mx), e1 = __expf(a1 - mx);
      float inv = 1.f / (e0 + e1);
      wpos[p] = e0 * inv;
      wpos[32 + p] = e1 * inv;
    }
  }
}

// ---------------------------------------------------------------------------
// Kernel T: transpose x (B,C,H,W) -> x_t (B,H,W,C). grid = B*H blocks x 256
// ---------------------------------------------------------------------------
__global__ __launch_bounds__(256) void transpose_kernel(
    const float* __restrict__ x, float* __restrict__ x_t) {
  __shared__ float tile[64][129];  // pad to kill bank conflicts
  int by = blockIdx.x;            // b*128 + y
  int b = by >> 7, y = by & 127;
  const float* xp = x + (size_t)b * (CIN_ * H_ * W_) + (size_t)y * W_;
  #pragma unroll
  for (int it = 0; it < 32; ++it) {
    int idx = threadIdx.x + it * 256;
    int c = idx >> 7, xw = idx & 127;
    tile[c][xw] = xp[(size_t)c * (H_ * W_) + xw];  // coalesced along xw
  }
  __syncthreads();
  float* xtp = x_t + ((size_t)b * (H_ * W_) + (size_t)y * W_) * CIN_;
  #pragma unroll
  for (int it = 0; it < 32; ++it) {
    int idx = threadIdx.x + it * 256;
    int xw = idx >> 6, c = idx & 63;
    xtp[idx] = tile[c][xw];  // contiguous store, conflict-free read
  }
}

// ---------------------------------------------------------------------------
// Kernel C: fused attention. One wave (64 lanes = channels) per output pos.
// grid = NPOS/4 blocks x 256 (4 waves/block, independent).
// ---------------------------------------------------------------------------
__global__ __launch_bounds__(256) void attn_kernel(
    const float* __restrict__ x_t, const float* __restrict__ M,
    const float* __restrict__ wpos, float* __restrict__ G) {
  int wave = threadIdx.x >> 6;
  int lane = threadIdx.x & 63;
  int pos = blockIdx.x * 4 + wave;   // 0..32767
  int b = pos >> 12;
  int ho = (pos >> 6) & 63;
  int wo = pos & 63;
  int y0 = 2 * ho, x0 = 2 * wo;

  const float* xb = x_t + (size_t)b * (H_ * W_ * CIN_);

  // q-pixel channel vector (coalesced 256B)
  float xq = xb[(size_t)(y0 * W_ + x0) * CIN_ + lane];

  // u[lane] = sum_a xq[a] * M[a*64 + lane]  (shfl broadcast + coalesced M)
  float u0 = 0.f, u1 = 0.f;
  #pragma unroll
  for (int a = 0; a < 64; a += 2) {
    float xa0 = __shfl(xq, a);
    float xa1 = __shfl(xq, a + 1);
    u0 = fmaf(xa0, M[a * 64 + lane], u0);
    u1 = fmaf(xa1, M[(a + 1) * 64 + lane], u1);
  }
  float u = u0 + u1;

  // load 25 tap vectors, per-lane partial scores
  float xv[25], s[25];
  #pragma unroll
  for (int p = 0; p < 25; ++p) {
    int i = p / 5, j = p % 5;
    int y = y0 - 2 + i, xw = x0 - 2 + j;
    bool valid = ((unsigned)y < (unsigned)H_) && ((unsigned)xw < (unsigned)W_);
    xv[p] = valid ? xb[(size_t)(y * W_ + xw) * CIN_ + lane] : 0.f;
    s[p] = u * xv[p];
  }

  // butterfly reduce all 25 scores across 64 lanes
  #pragma unroll
  for (int off = 32; off > 0; off >>= 1) {
    #pragma unroll
    for (int p = 0; p < 25; ++p) s[p] += __shfl_xor(s[p], off);
  }

  // softmax over 25 (redundant per lane; OOB taps correctly contribute exp(0))
  float m = s[0];
  #pragma unroll
  for (int p = 1; p < 25; ++p) m = fmaxf(m, s[p]);
  float Z = 0.f;
  #pragma unroll
  for (int p = 0; p < 25; ++p) { s[p] = __expf(s[p] - m); Z += s[p]; }
  float rZ = 1.f / Z;

  // g_m[lane] = sum_p attn_p * wpos[m,p] * xv[p]
  float g0 = 0.f, g1 = 0.f;
  #pragma unroll
  for (int p = 0; p < 25; ++p) {
    float ap = s[p] * rZ;
    g0 = fmaf(ap * wpos[p], xv[p], g0);
    g1 = fmaf(ap * wpos[32 + p], xv[p], g1);
  }
  G[(size_t)pos * 128 + lane] = g0;
  G[(size_t)pos * 128 + 64 + lane] = g1;
}

// ---------------------------------------------------------------------------
// Kernel D v2: out[c,pos] = sum_k Wv[c][k] * G[pos][k]   (Wv = w_v as 128x128,
// since rows 2c,2c+1 are contiguous and G[pos] = [g0|g1]).
// Block = 64 pos x 64 ch. Grid = 1024 (512 pos-tiles x 2 ch-halves).
// w_v half staged in LDS (32 KB), read as same-address b128 broadcasts.
// lane = pos (coalesced G loads + out stores). 4 blocks/CU, 16 waves/CU.
// ---------------------------------------------------------------------------
__global__ __launch_bounds__(256, 4) void out_kernel(
    const float* __restrict__ G, const float* __restrict__ w_v,
    float* __restrict__ out) {
  __shared__ float Wl[64][128];  // broadcast reads -> no conflicts, no pad

  int pos_tile = blockIdx.x >> 1;
  int ch_half  = blockIdx.x & 1;
  int c0 = ch_half * 64;
  int pos0 = pos_tile * 64;

  // stage w_v[c0..c0+64)[0..128) into LDS, coalesced float4
  {
    const float4* wsrc = (const float4*)(w_v + (size_t)c0 * 128);
    float4* wdst = (float4*)(&Wl[0][0]);
    #pragma unroll
    for (int i = 0; i < 8; ++i)
      wdst[threadIdx.x + i * 256] = wsrc[threadIdx.x + i * 256];
  }
  __syncthreads();

  int wave = threadIdx.x >> 6;    // 0..3 -> 16 channels each
  int lane = threadIdx.x & 63;    // = pos offset
  int pos = pos0 + lane;
  const float* Gp = G + (size_t)pos * 128;

  int b = pos0 >> 12;
  int hw0 = pos0 & 4095;
  float* op = out + (size_t)b * (OC_ * HO_ * WO_) + hw0 + lane;

  #pragma unroll
  for (int cc = 0; cc < 16; cc += 8) {
    float acc[8] = {0.f, 0.f, 0.f, 0.f, 0.f, 0.f, 0.f, 0.f};
    #pragma unroll
    for (int kc = 0; kc < 128; kc += 32) {
      // G chunk: 32 floats per lane (8 x float4), L1/L2-resident tile
      float gk[32];
      #pragma unroll
      for (int q = 0; q < 8; ++q) {
        float4 t = *reinterpret_cast<const float4*>(Gp + kc + q * 4);
        gk[q * 4] = t.x; gk[q * 4 + 1] = t.y;
        gk[q * 4 + 2] = t.z; gk[q * 4 + 3] = t.w;
      }
      #pragma unroll
      for (int k4 = 0; k4 < 32; k4 += 4) {
        #pragma unroll
        for (int j = 0; j < 8; ++j) {
          const float4 wv = *reinterpret_cast<const float4*>(
              &Wl[wave * 16 + cc + j][kc + k4]);
          acc[j] = fmaf(wv.x, gk[k4],     acc[j]);
          acc[j] = fmaf(wv.y, gk[k4 + 1], acc[j]);
          acc[j] = fmaf(wv.z, gk[k4 + 2], acc[j]);
          acc[j] = fmaf(wv.w, gk[k4 + 3], acc[j]);
        }
      }
    }
    #pragma unroll
    for (int j = 0; j < 8; ++j) {
      int c = c0 + wave * 16 + cc + j;
      op[(size_t)c * (HO_ * WO_)] = acc[j];
    }
  }
}

// ---------------------------------------------------------------------------
extern "C" void kernel_launch(void* const* d_in, const int* in_sizes, int n_in,
                              void* d_out, int out_size, void* d_ws, size_t ws_size,
                              hipStream_t stream) {
  const float* x       = (const float*)d_in[0];
  const float* w_q     = (const float*)d_in[1];
  const float* w_k     = (const float*)d_in[2];
  const float* w_v     = (const float*)d_in[3];
  const float* row_emb = (const float*)d_in[4];
  const float* col_emb = (const float*)d_in[5];
  const float* mix_emb = (const float*)d_in[6];
  float* out = (float*)d_out;

  float* ws   = (float*)d_ws;
  float* x_t  = ws + XT_OFF;
  float* G    = ws + G_OFF;
  float* M    = ws + M_OFF;
  float* wpos = ws + WPOS_OFF;

  prep_kernel<<<17, 256, 0, stream>>>(w_q, w_k, row_emb, col_emb, mix_emb, M, wpos);
  transpose_kernel<<<B_ * H_, 256, 0, stream>>>(x, x_t);
  attn_kernel<<<NPOS / 4, 256, 0, stream>>>(x_t, M, wpos, G);
  out_kernel<<<1024, 256, 0, stream>>>(G, w_v, out);
}

// Round 3
// 127.036 us; speedup vs baseline: 1.8958x; 1.2688x over previous
//
#include <hip/hip_runtime.h>

// Problem constants
#define B_    8
#define CIN_  64
#define H_    128
#define W_    128
#define OC_   128
#define HO_   64
#define WO_   64
#define NPOS  (B_ * HO_ * WO_)   // 32768

// ws layout (float offsets)
#define XT_OFF   0            // x_t: (B,H,W,CIN) = 8*128*128*64 = 8388608 floats
#define G_OFF    8388608      // G:   (NPOS,128)  = 4194304 floats
#define M_OFF    12582912     // M:   64*64 = 4096 floats
#define WPOS_OFF 12587008     // wpos0[25] at +0, wpos1[25] at +32

// ---------------------------------------------------------------------------
// VALU-pipe cross-lane helpers (no ds_bpermute / ds_swizzle)
// ---------------------------------------------------------------------------
template <int CTRL>
__device__ __forceinline__ float dpp_add(float x) {
  int y = __builtin_amdgcn_update_dpp(0, __float_as_int(x), CTRL, 0xf, 0xf, true);
  return x + __int_as_float(y);
}

// 64-lane allsum, all on VALU pipe; returns wave-uniform total.
__device__ __forceinline__ float wave_allsum(float x) {
  x = dpp_add<0x121>(x);  // row_ror:1
  x = dpp_add<0x122>(x);  // row_ror:2
  x = dpp_add<0x124>(x);  // row_ror:4
  x = dpp_add<0x128>(x);  // row_ror:8  -> each lane holds its row-16 sum
  x = dpp_add<0x142>(x);  // row_bcast15: rows 1,3 += rows 0,2 sums
  x = dpp_add<0x143>(x);  // row_bcast31: lane 63 = full 64-lane sum
  return __int_as_float(__builtin_amdgcn_readlane(__float_as_int(x), 63));
}

__device__ __forceinline__ float lane_bcast(float x, int lane) {
  return __int_as_float(__builtin_amdgcn_readlane(__float_as_int(x), lane));
}

// ---------------------------------------------------------------------------
// Kernel A: M = W_q^T W_k (64x64) and wpos (2x25 softmax over mixtures)
// ---------------------------------------------------------------------------
__global__ __launch_bounds__(256) void prep_kernel(
    const float* __restrict__ w_q, const float* __restrict__ w_k,
    const float* __restrict__ row_emb, const float* __restrict__ col_emb,
    const float* __restrict__ mix_emb, float* __restrict__ M,
    float* __restrict__ wpos) {
  if (blockIdx.x < 16) {
    int idx = blockIdx.x * 256 + threadIdx.x;  // 0..4095
    int a = idx >> 6;
    int bb = idx & 63;
    float acc = 0.f;
    #pragma unroll 8
    for (int o = 0; o < 128; ++o)
      acc = fmaf(w_q[o * 64 + a], w_k[o * 64 + bb], acc);
    M[idx] = acc;
  } else {
    int p = threadIdx.x;
    if (p < 25) {
      int i = p / 5, j = p % 5;
      float a0 = 0.f, a1 = 0.f;
      for (int c = 0; c < 128; ++c) {
        float rc = row_emb[c * 5 + i] + col_emb[c * 5 + j];
        a0 = fmaf(rc, mix_emb[c * 2 + 0], a0);
        a1 = fmaf(rc, mix_emb[c * 2 + 1], a1);
      }
      float mx = fmaxf(a0, a1);
      float e0 = __expf(a0 - mx), e1 = __expf(a1 - mx);
      float inv = 1.f / (e0 + e1);
      wpos[p] = e0 * inv;
      wpos[32 + p] = e1 * inv;
    }
  }
}

// ---------------------------------------------------------------------------
// Kernel T: transpose x (B,C,H,W) -> x_t (B,H,W,C). grid = B*H blocks x 256
// ---------------------------------------------------------------------------
__global__ __launch_bounds__(256) void transpose_kernel(
    const float* __restrict__ x, float* __restrict__ x_t) {
  __shared__ float tile[64][129];
  int by = blockIdx.x;
  int b = by >> 7, y = by & 127;
  const float* xp = x + (size_t)b * (CIN_ * H_ * W_) + (size_t)y * W_;
  #pragma unroll
  for (int it = 0; it < 32; ++it) {
    int idx = threadIdx.x + it * 256;
    int c = idx >> 7, xw = idx & 127;
    tile[c][xw] = xp[(size_t)c * (H_ * W_) + xw];
  }
  __syncthreads();
  float* xtp = x_t + ((size_t)b * (H_ * W_) + (size_t)y * W_) * CIN_;
  #pragma unroll
  for (int it = 0; it < 32; ++it) {
    int idx = threadIdx.x + it * 256;
    int xw = idx >> 6, c = idx & 63;
    xtp[idx] = tile[c][xw];
  }
}

// ---------------------------------------------------------------------------
// Kernel C v3: fused attention. One wave (64 lanes = channels) per position.
// Cross-lane via DPP/readlane (VALU pipe) -- zero LDS-pipe traffic.
// ---------------------------------------------------------------------------
__global__ __launch_bounds__(256) void attn_kernel(
    const float* __restrict__ x_t, const float* __restrict__ M,
    const float* __restrict__ wpos, float* __restrict__ G) {
  int wave = threadIdx.x >> 6;
  int lane = threadIdx.x & 63;
  int pos = blockIdx.x * 4 + wave;
  int b = pos >> 12;
  int ho = (pos >> 6) & 63;
  int wo = pos & 63;
  int y0 = 2 * ho, x0 = 2 * wo;

  const float* xb = x_t + (size_t)b * (H_ * W_ * CIN_);

  // q-pixel channel vector (coalesced 256B)
  float xq = xb[(size_t)(y0 * W_ + x0) * CIN_ + lane];

  // u[lane] = sum_a xq[a] * M[a*64 + lane]; broadcast via readlane (VALU)
  float u0 = 0.f, u1 = 0.f;
  #pragma unroll
  for (int a = 0; a < 64; a += 2) {
    float xa0 = lane_bcast(xq, a);
    float xa1 = lane_bcast(xq, a + 1);
    u0 = fmaf(xa0, M[a * 64 + lane], u0);
    u1 = fmaf(xa1, M[(a + 1) * 64 + lane], u1);
  }
  float u = u0 + u1;

  // load 25 tap vectors, per-lane partial scores
  float xv[25], s[25];
  #pragma unroll
  for (int p = 0; p < 25; ++p) {
    int i = p / 5, j = p % 5;
    int y = y0 - 2 + i, xw = x0 - 2 + j;
    bool valid = ((unsigned)y < (unsigned)H_) && ((unsigned)xw < (unsigned)W_);
    xv[p] = valid ? xb[(size_t)(y * W_ + xw) * CIN_ + lane] : 0.f;
    s[p] = u * xv[p];
  }

  // 64-lane allsum of all 25 scores on the VALU pipe
  #pragma unroll
  for (int p = 0; p < 25; ++p) s[p] = wave_allsum(s[p]);

  // softmax over 25 (uniform values, redundant per lane)
  float m = s[0];
  #pragma unroll
  for (int p = 1; p < 25; ++p) m = fmaxf(m, s[p]);
  float Z = 0.f;
  #pragma unroll
  for (int p = 0; p < 25; ++p) { s[p] = __expf(s[p] - m); Z += s[p]; }
  float rZ = 1.f / Z;

  // g_m[lane] = sum_p attn_p * wpos[m,p] * xv[p]
  float g0 = 0.f, g1 = 0.f;
  #pragma unroll
  for (int p = 0; p < 25; ++p) {
    float ap = s[p] * rZ;
    g0 = fmaf(ap * wpos[p], xv[p], g0);
    g1 = fmaf(ap * wpos[32 + p], xv[p], g1);
  }
  G[(size_t)pos * 128 + lane] = g0;
  G[(size_t)pos * 128 + 64 + lane] = g1;
}

// ---------------------------------------------------------------------------
// Kernel D v2: out[c,pos] = sum_k Wv[c][k] * G[pos][k]
// ---------------------------------------------------------------------------
__global__ __launch_bounds__(256, 4) void out_kernel(
    const float* __restrict__ G, const float* __restrict__ w_v,
    float* __restrict__ out) {
  __shared__ float Wl[64][128];

  int pos_tile = blockIdx.x >> 1;
  int ch_half  = blockIdx.x & 1;
  int c0 = ch_half * 64;
  int pos0 = pos_tile * 64;

  {
    const float4* wsrc = (const float4*)(w_v + (size_t)c0 * 128);
    float4* wdst = (float4*)(&Wl[0][0]);
    #pragma unroll
    for (int i = 0; i < 8; ++i)
      wdst[threadIdx.x + i * 256] = wsrc[threadIdx.x + i * 256];
  }
  __syncthreads();

  int wave = threadIdx.x >> 6;
  int lane = threadIdx.x & 63;
  int pos = pos0 + lane;
  const float* Gp = G + (size_t)pos * 128;

  int b = pos0 >> 12;
  int hw0 = pos0 & 4095;
  float* op = out + (size_t)b * (OC_ * HO_ * WO_) + hw0 + lane;

  #pragma unroll
  for (int cc = 0; cc < 16; cc += 8) {
    float acc[8] = {0.f, 0.f, 0.f, 0.f, 0.f, 0.f, 0.f, 0.f};
    #pragma unroll
    for (int kc = 0; kc < 128; kc += 32) {
      float gk[32];
      #pragma unroll
      for (int q = 0; q < 8; ++q) {
        float4 t = *reinterpret_cast<const float4*>(Gp + kc + q * 4);
        gk[q * 4] = t.x; gk[q * 4 + 1] = t.y;
        gk[q * 4 + 2] = t.z; gk[q * 4 + 3] = t.w;
      }
      #pragma unroll
      for (int k4 = 0; k4 < 32; k4 += 4) {
        #pragma unroll
        for (int j = 0; j < 8; ++j) {
          const float4 wv = *reinterpret_cast<const float4*>(
              &Wl[wave * 16 + cc + j][kc + k4]);
          acc[j] = fmaf(wv.x, gk[k4],     acc[j]);
          acc[j] = fmaf(wv.y, gk[k4 + 1], acc[j]);
          acc[j] = fmaf(wv.z, gk[k4 + 2], acc[j]);
          acc[j] = fmaf(wv.w, gk[k4 + 3], acc[j]);
        }
      }
    }
    #pragma unroll
    for (int j = 0; j < 8; ++j) {
      int c = c0 + wave * 16 + cc + j;
      op[(size_t)c * (HO_ * WO_)] = acc[j];
    }
  }
}

// ---------------------------------------------------------------------------
extern "C" void kernel_launch(void* const* d_in, const int* in_sizes, int n_in,
                              void* d_out, int out_size, void* d_ws, size_t ws_size,
                              hipStream_t stream) {
  const float* x       = (const float*)d_in[0];
  const float* w_q     = (const float*)d_in[1];
  const float* w_k     = (const float*)d_in[2];
  const float* w_v     = (const float*)d_in[3];
  const float* row_emb = (const float*)d_in[4];
  const float* col_emb = (const float*)d_in[5];
  const float* mix_emb = (const float*)d_in[6];
  float* out = (float*)d_out;

  float* ws   = (float*)d_ws;
  float* x_t  = ws + XT_OFF;
  float* G    = ws + G_OFF;
  float* M    = ws + M_OFF;
  float* wpos = ws + WPOS_OFF;

  prep_kernel<<<17, 256, 0, stream>>>(w_q, w_k, row_emb, col_emb, mix_emb, M, wpos);
  transpose_kernel<<<B_ * H_, 256, 0, stream>>>(x, x_t);
  attn_kernel<<<NPOS / 4, 256, 0, stream>>>(x_t, M, wpos, G);
  out_kernel<<<1024, 256, 0, stream>>>(G, w_v, out);
}

// Round 4
// 79.113 us; speedup vs baseline: 3.0442x; 1.6058x over previous
//
#include <hip/hip_runtime.h>

typedef unsigned int  uint_;
typedef unsigned short u16;

// Problem constants
#define B_    8
#define CIN_  64
#define H_    128
#define W_    128
#define OC_   128
#define HO_   64
#define WO_   64
#define NPOS  (B_ * HO_ * WO_)   // 32768

// ws layout (float offsets)
#define XT_OFF   0            // x_t: (B,H,W,CIN) fp32 = 8388608 floats
#define G_OFF    8388608      // G: (NPOS,128) bf16 = 4194304 u16 = 2097152 floats
#define WHI_OFF  10485760     // Wv hi frags: 16384 u16 (canonical A-frag order)
#define WLO_OFF  10493952     // Wv lo frags: 16384 u16
#define M_OFF    12582912     // M: 64*64 fp32
#define WPOS_OFF 12587008     // wpos0[25] at +0, wpos1[25] at +32

// ---------------------------------------------------------------------------
// helpers
// ---------------------------------------------------------------------------
__device__ __forceinline__ u16 f2bf(float x) {          // RNE float->bf16
  uint_ u = __float_as_uint(x);
  u += 0x7FFFu + ((u >> 16) & 1u);
  return (u16)(u >> 16);
}

template <int CTRL>
__device__ __forceinline__ float dpp_add(float x) {
  int y = __builtin_amdgcn_update_dpp(0, __float_as_int(x), CTRL, 0xf, 0xf, true);
  return x + __int_as_float(y);
}

// 64-lane allsum on the VALU pipe; returns wave-uniform total.
__device__ __forceinline__ float wave_allsum(float x) {
  x = dpp_add<0x121>(x);  // row_ror:1
  x = dpp_add<0x122>(x);  // row_ror:2
  x = dpp_add<0x124>(x);  // row_ror:4
  x = dpp_add<0x128>(x);  // row_ror:8
  x = dpp_add<0x142>(x);  // row_bcast15
  x = dpp_add<0x143>(x);  // row_bcast31
  return __int_as_float(__builtin_amdgcn_readlane(__float_as_int(x), 63));
}

__device__ __forceinline__ float lane_bcast(float x, int lane) {
  return __int_as_float(__builtin_amdgcn_readlane(__float_as_int(x), lane));
}

// ---------------------------------------------------------------------------
// Kernel A: M = W_q^T W_k, wpos softmax, and Wv hi/lo bf16 A-fragment prep.
// grid = 33 blocks x 256
// ---------------------------------------------------------------------------
__global__ __launch_bounds__(256) void prep_kernel(
    const float* __restrict__ w_q, const float* __restrict__ w_k,
    const float* __restrict__ w_v,
    const float* __restrict__ row_emb, const float* __restrict__ col_emb,
    const float* __restrict__ mix_emb, float* __restrict__ M,
    float* __restrict__ wpos, u16* __restrict__ WhiF, u16* __restrict__ WloF) {
  if (blockIdx.x < 16) {
    int idx = blockIdx.x * 256 + threadIdx.x;  // 0..4095
    int a = idx >> 6;
    int bb = idx & 63;
    float acc = 0.f;
    #pragma unroll 8
    for (int o = 0; o < 128; ++o)
      acc = fmaf(w_q[o * 64 + a], w_k[o * 64 + bb], acc);
    M[idx] = acc;
  } else if (blockIdx.x == 16) {
    int p = threadIdx.x;
    if (p < 25) {
      int i = p / 5, j = p % 5;
      float a0 = 0.f, a1 = 0.f;
      for (int c = 0; c < 128; ++c) {
        float rc = row_emb[c * 5 + i] + col_emb[c * 5 + j];
        a0 = fmaf(rc, mix_emb[c * 2 + 0], a0);
        a1 = fmaf(rc, mix_emb[c * 2 + 1], a1);
      }
      float mx = fmaxf(a0, a1);
      float e0 = __expf(a0 - mx), e1 = __expf(a1 - mx);
      float inv = 1.f / (e0 + e1);
      wpos[p] = e0 * inv;
      wpos[32 + p] = e1 * inv;
    }
  } else {
    // Wv[c][k] = w_v[c*128+k] (rows 2c,2c+1 contiguous). Split hi/lo bf16 and
    // store in canonical 16x16x32 A-fragment order:
    // lane = (c&15) + 16*((k>>3)&3), reg j = k&7, frag (ks=k>>5, m=c>>4).
    int t = (blockIdx.x - 17) * 256 + threadIdx.x;  // 0..4095
    #pragma unroll
    for (int e = 0; e < 4; ++e) {
      int elem = t * 4 + e;            // = c*128 + k
      int c = elem >> 7, k = elem & 127;
      float w = w_v[elem];
      u16 hi = f2bf(w);
      float hif = __uint_as_float((uint_)hi << 16);
      u16 lo = f2bf(w - hif);
      int m = c >> 4, lr = c & 15;
      int ks = k >> 5, q = (k >> 3) & 3, j = k & 7;
      int off = ((ks * 8 + m) * 64 + (lr + 16 * q)) * 8 + j;
      WhiF[off] = hi;
      WloF[off] = lo;
    }
  }
}

// ---------------------------------------------------------------------------
// Kernel T: transpose x (B,C,H,W) -> x_t (B,H,W,C). grid = B*H blocks x 256
// ---------------------------------------------------------------------------
__global__ __launch_bounds__(256) void transpose_kernel(
    const float* __restrict__ x, float* __restrict__ x_t) {
  __shared__ float tile[64][129];
  int by = blockIdx.x;
  int b = by >> 7, y = by & 127;
  const float* xp = x + (size_t)b * (CIN_ * H_ * W_) + (size_t)y * W_;
  #pragma unroll
  for (int it = 0; it < 32; ++it) {
    int idx = threadIdx.x + it * 256;
    int c = idx >> 7, xw = idx & 127;
    tile[c][xw] = xp[(size_t)c * (H_ * W_) + xw];
  }
  __syncthreads();
  float* xtp = x_t + ((size_t)b * (H_ * W_) + (size_t)y * W_) * CIN_;
  #pragma unroll
  for (int it = 0; it < 32; ++it) {
    int idx = threadIdx.x + it * 256;
    int xw = idx >> 6, c = idx & 63;
    xtp[idx] = tile[c][xw];
  }
}

// ---------------------------------------------------------------------------
// Kernel C: fused attention (DPP cross-lane). Writes G as bf16.
// ---------------------------------------------------------------------------
__global__ __launch_bounds__(256) void attn_kernel(
    const float* __restrict__ x_t, const float* __restrict__ M,
    const float* __restrict__ wpos, u16* __restrict__ GB) {
  int wave = threadIdx.x >> 6;
  int lane = threadIdx.x & 63;
  int pos = blockIdx.x * 4 + wave;
  int b = pos >> 12;
  int ho = (pos >> 6) & 63;
  int wo = pos & 63;
  int y0 = 2 * ho, x0 = 2 * wo;

  const float* xb = x_t + (size_t)b * (H_ * W_ * CIN_);

  float xq = xb[(size_t)(y0 * W_ + x0) * CIN_ + lane];

  float u0 = 0.f, u1 = 0.f;
  #pragma unroll
  for (int a = 0; a < 64; a += 2) {
    float xa0 = lane_bcast(xq, a);
    float xa1 = lane_bcast(xq, a + 1);
    u0 = fmaf(xa0, M[a * 64 + lane], u0);
    u1 = fmaf(xa1, M[(a + 1) * 64 + lane], u1);
  }
  float u = u0 + u1;

  float xv[25], s[25];
  #pragma unroll
  for (int p = 0; p < 25; ++p) {
    int i = p / 5, j = p % 5;
    int y = y0 - 2 + i, xw = x0 - 2 + j;
    bool valid = ((unsigned)y < (unsigned)H_) && ((unsigned)xw < (unsigned)W_);
    xv[p] = valid ? xb[(size_t)(y * W_ + xw) * CIN_ + lane] : 0.f;
    s[p] = u * xv[p];
  }

  #pragma unroll
  for (int p = 0; p < 25; ++p) s[p] = wave_allsum(s[p]);

  float m = s[0];
  #pragma unroll
  for (int p = 1; p < 25; ++p) m = fmaxf(m, s[p]);
  float Z = 0.f;
  #pragma unroll
  for (int p = 0; p < 25; ++p) { s[p] = __expf(s[p] - m); Z += s[p]; }
  float rZ = 1.f / Z;

  float g0 = 0.f, g1 = 0.f;
  #pragma unroll
  for (int p = 0; p < 25; ++p) {
    float ap = s[p] * rZ;
    g0 = fmaf(ap * wpos[p], xv[p], g0);
    g1 = fmaf(ap * wpos[32 + p], xv[p], g1);
  }
  GB[((size_t)pos << 7) + lane] = f2bf(g0);
  GB[((size_t)pos << 7) + 64 + lane] = f2bf(g1);
}

// ---------------------------------------------------------------------------
// Kernel D v3 (MFMA): out[c][pos] = sum_k (Whi+Wlo)[c][k] * G[pos][k], fp32 acc.
// Block = 4 waves; wave = 32 pos x 128 ch. Grid = 256. Zero LDS.
// ---------------------------------------------------------------------------
typedef __attribute__((ext_vector_type(8))) short bfrag;
typedef __attribute__((ext_vector_type(4))) float f4;

__global__ __launch_bounds__(256) void out_kernel(
    const u16* __restrict__ GB, const u16* __restrict__ WhiF,
    const u16* __restrict__ WloF, float* __restrict__ out) {
  int wave = threadIdx.x >> 6, lane = threadIdx.x & 63;
  int lr = lane & 15, q = lane >> 4;
  int pos0 = blockIdx.x * 128 + wave * 32;

  f4 acc[8][2];
  #pragma unroll
  for (int m = 0; m < 8; ++m) {
    acc[m][0] = (f4)0.f;
    acc[m][1] = (f4)0.f;
  }

  #pragma unroll
  for (int ks = 0; ks < 4; ++ks) {
    // B-frags: lane holds pos col (lane&15), k = ks*32 + (lane>>4)*8 + j
    bfrag b0 = *reinterpret_cast<const bfrag*>(
        GB + (((size_t)(pos0 + lr)) << 7) + ks * 32 + q * 8);
    bfrag b1 = *reinterpret_cast<const bfrag*>(
        GB + (((size_t)(pos0 + 16 + lr)) << 7) + ks * 32 + q * 8);
    const u16* hbase = WhiF + (ks * 8 * 64 + lane) * 8;
    const u16* lbase = WloF + (ks * 8 * 64 + lane) * 8;
    #pragma unroll
    for (int m = 0; m < 8; ++m) {
      bfrag ah = *reinterpret_cast<const bfrag*>(hbase + m * 512);
      bfrag al = *reinterpret_cast<const bfrag*>(lbase + m * 512);
      acc[m][0] = __builtin_amdgcn_mfma_f32_16x16x32_bf16(ah, b0, acc[m][0], 0, 0, 0);
      acc[m][1] = __builtin_amdgcn_mfma_f32_16x16x32_bf16(ah, b1, acc[m][1], 0, 0, 0);
      acc[m][0] = __builtin_amdgcn_mfma_f32_16x16x32_bf16(al, b0, acc[m][0], 0, 0, 0);
      acc[m][1] = __builtin_amdgcn_mfma_f32_16x16x32_bf16(al, b1, acc[m][1], 0, 0, 0);
    }
  }

  // D mapping: col = lane&15 (pos), row = (lane>>4)*4 + r (ch within m-tile)
  int b = pos0 >> 12;
  int hw = pos0 & 4095;
  float* op = out + (size_t)b * (OC_ * HO_ * WO_) + hw;
  #pragma unroll
  for (int m = 0; m < 8; ++m) {
    #pragma unroll
    for (int r = 0; r < 4; ++r) {
      int c = m * 16 + q * 4 + r;
      op[(size_t)c * 4096 + lr] = acc[m][0][r];
      op[(size_t)c * 4096 + 16 + lr] = acc[m][1][r];
    }
  }
}

// ---------------------------------------------------------------------------
extern "C" void kernel_launch(void* const* d_in, const int* in_sizes, int n_in,
                              void* d_out, int out_size, void* d_ws, size_t ws_size,
                              hipStream_t stream) {
  const float* x       = (const float*)d_in[0];
  const float* w_q     = (const float*)d_in[1];
  const float* w_k     = (const float*)d_in[2];
  const float* w_v     = (const float*)d_in[3];
  const float* row_emb = (const float*)d_in[4];
  const float* col_emb = (const float*)d_in[5];
  const float* mix_emb = (const float*)d_in[6];
  float* out = (float*)d_out;

  float* ws   = (float*)d_ws;
  float* x_t  = ws + XT_OFF;
  u16*   GB   = (u16*)(ws + G_OFF);
  u16*   WhiF = (u16*)(ws + WHI_OFF);
  u16*   WloF = (u16*)(ws + WLO_OFF);
  float* M    = ws + M_OFF;
  float* wpos = ws + WPOS_OFF;

  prep_kernel<<<33, 256, 0, stream>>>(w_q, w_k, w_v, row_emb, col_emb, mix_emb,
                                      M, wpos, WhiF, WloF);
  transpose_kernel<<<B_ * H_, 256, 0, stream>>>(x, x_t);
  attn_kernel<<<NPOS / 4, 256, 0, stream>>>(x_t, M, wpos, GB);
  out_kernel<<<256, 256, 0, stream>>>(GB, WhiF, WloF, out);
}

// Round 5
// 58.531 us; speedup vs baseline: 4.1146x; 1.3516x over previous
//
#include <hip/hip_runtime.h>

typedef unsigned int   uint_;
typedef unsigned short u16;

// Problem constants
#define B_    8
#define CIN_  64
#define H_    128
#define W_    128
#define OC_   128
#define HO_   64
#define WO_   64
#define NPOS  (B_ * HO_ * WO_)   // 32768

// ws layout (float offsets)
#define XBT_OFF  0          // bf16 x_bt (B,H,W,64) = 4194304 floats
#define U_OFF    4194304    // f32 U[NPOS][64]      = 2097152 floats
#define GB_OFF   6291456    // bf16 GB[NPOS][128]   = 2097152 floats
#define MHI_OFF  8388608    // u16[4096]  = 2048 floats
#define MLO_OFF  8390656
#define WHI_OFF  8392704    // u16[16384] = 8192 floats
#define WLO_OFF  8400896
#define WPOS_OFF 8409088    // wpos0[25] @ +0, wpos1[25] @ +32

// ---------------------------------------------------------------------------
// helpers
// ---------------------------------------------------------------------------
__device__ __forceinline__ u16 f2bf(float x) {          // RNE float->bf16
  uint_ u = __float_as_uint(x);
  u += 0x7FFFu + ((u >> 16) & 1u);
  return (u16)(u >> 16);
}
__device__ __forceinline__ uint_ pack2bf(float lo, float hi) {
  return ((uint_)f2bf(hi) << 16) | (uint_)f2bf(lo);
}

template <int CTRL>
__device__ __forceinline__ float dpp_add(float x) {
  int y = __builtin_amdgcn_update_dpp(0, __float_as_int(x), CTRL, 0xf, 0xf, true);
  return x + __int_as_float(y);
}

typedef __attribute__((ext_vector_type(8))) short bfrag;
typedef __attribute__((ext_vector_type(4))) float f4;

// ---------------------------------------------------------------------------
// Kernel A (prep): M-frags (hi/lo), wpos softmax, Wv-frags (hi/lo).
// grid = 33 x 256.  M never materialized: each thread computes its dot.
// A-frag layout (16x16x32): slot lane = (i&15)+16*((k>>3)&3), reg = k&7.
// ---------------------------------------------------------------------------
__global__ __launch_bounds__(256) void prep_kernel(
    const float* __restrict__ w_q, const float* __restrict__ w_k,
    const float* __restrict__ w_v,
    const float* __restrict__ row_emb, const float* __restrict__ col_emb,
    const float* __restrict__ mix_emb,
    u16* __restrict__ MhiF, u16* __restrict__ MloF,
    u16* __restrict__ WhiF, u16* __restrict__ WloF,
    float* __restrict__ wpos) {
  if (blockIdx.x < 16) {
    // M[a][c] = sum_o w_q[o,a] * w_k[o,c]  -> A-frag (i=c, k=a), 4 m-tiles
    int idx = blockIdx.x * 256 + threadIdx.x;  // 0..4095
    int a = idx >> 6, c = idx & 63;
    float acc = 0.f;
    #pragma unroll 8
    for (int o = 0; o < 128; ++o)
      acc = fmaf(w_q[o * 64 + a], w_k[o * 64 + c], acc);
    u16 hi = f2bf(acc);
    float hif = __uint_as_float((uint_)hi << 16);
    u16 lo = f2bf(acc - hif);
    int m = c >> 4, lr = c & 15;
    int ks = a >> 5, q = (a >> 3) & 3, jr = a & 7;
    int off = ((ks * 4 + m) * 64 + (lr + 16 * q)) * 8 + jr;
    MhiF[off] = hi;
    MloF[off] = lo;
  } else if (blockIdx.x == 16) {
    int p = threadIdx.x;
    if (p < 25) {
      int i = p / 5, j = p % 5;
      float a0 = 0.f, a1 = 0.f;
      for (int c = 0; c < 128; ++c) {
        float rc = row_emb[c * 5 + i] + col_emb[c * 5 + j];
        a0 = fmaf(rc, mix_emb[c * 2 + 0], a0);
        a1 = fmaf(rc, mix_emb[c * 2 + 1], a1);
      }
      float mx = fmaxf(a0, a1);
      float e0 = __expf(a0 - mx), e1 = __expf(a1 - mx);
      float inv = 1.f / (e0 + e1);
      wpos[p] = e0 * inv;
      wpos[32 + p] = e1 * inv;
    }
  } else {
    // Wv[c][k] = w_v[c*128+k]; A-frag (i=c, k), 8 m-tiles (c=128)
    int t = (blockIdx.x - 17) * 256 + threadIdx.x;  // 0..4095
    #pragma unroll
    for (int e = 0; e < 4; ++e) {
      int elem = t * 4 + e;            // = c*128 + k
      int c = elem >> 7, k = elem & 127;
      float w = w_v[elem];
      u16 hi = f2bf(w);
      float hif = __uint_as_float((uint_)hi << 16);
      u16 lo = f2bf(w - hif);
      int m = c >> 4, lr = c & 15;
      int ks = k >> 5, q = (k >> 3) & 3, j = k & 7;
      int off = ((ks * 8 + m) * 64 + (lr + 16 * q)) * 8 + j;
      WhiF[off] = hi;
      WloF[off] = lo;
    }
  }
}

// ---------------------------------------------------------------------------
// Kernel T: transpose x (B,C,H,W) f32 -> x_bt (B,H,W,C) bf16. grid = B*H x 256
// ---------------------------------------------------------------------------
__global__ __launch_bounds__(256) void transpose_kernel(
    const float* __restrict__ x, u16* __restrict__ xbt) {
  __shared__ float tile[64][129];
  int by = blockIdx.x;
  int b = by >> 7, y = by & 127;
  const float* xp = x + (size_t)b * (CIN_ * H_ * W_) + (size_t)y * W_;
  #pragma unroll
  for (int it = 0; it < 32; ++it) {
    int idx = threadIdx.x + it * 256;
    int c = idx >> 7, xw = idx & 127;
    tile[c][xw] = xp[(size_t)c * (H_ * W_) + xw];
  }
  __syncthreads();
  uint_* dst = (uint_*)(xbt + ((size_t)(b * H_ + y)) * (W_ * 64));
  #pragma unroll
  for (int it = 0; it < 16; ++it) {
    int idx = threadIdx.x + it * 256;   // = xw*32 + cp
    int xw = idx >> 5, cp = idx & 31;
    dst[idx] = pack2bf(tile[2 * cp][xw], tile[2 * cp + 1][xw]);
  }
}

// ---------------------------------------------------------------------------
// Kernel U (MFMA): U[pos][c] = sum_a M[a][c] * xq[pos][a].
// A = M-frags (hi/lo), B = xq bf16 (direct from x_bt), D -> U f32.
// wave = one 16-pos tile. grid = 512 x 256 (4 waves).
// ---------------------------------------------------------------------------
__global__ __launch_bounds__(256) void u_kernel(
    const u16* __restrict__ xbt, const u16* __restrict__ MhiF,
    const u16* __restrict__ MloF, float* __restrict__ U) {
  int wave = threadIdx.x >> 6, lane = threadIdx.x & 63;
  int lr = lane & 15, q = lane >> 4;
  int tile = blockIdx.x * 4 + wave;   // 0..2047
  int pos0 = tile * 16;
  int pos = pos0 + lr;                // B-frag col j = lr
  int b = pos >> 12, ho = (pos >> 6) & 63, wo = pos & 63;
  const u16* xq = xbt + ((size_t)(b * H_ + 2 * ho) * W_ + 2 * wo) * 64;

  f4 acc[4];
  #pragma unroll
  for (int m = 0; m < 4; ++m) acc[m] = (f4)0.f;

  #pragma unroll
  for (int ks = 0; ks < 2; ++ks) {
    bfrag bb = *reinterpret_cast<const bfrag*>(xq + ks * 32 + q * 8);
    #pragma unroll
    for (int m = 0; m < 4; ++m) {
      bfrag ah = *reinterpret_cast<const bfrag*>(MhiF + ((ks * 4 + m) * 64 + lane) * 8);
      bfrag al = *reinterpret_cast<const bfrag*>(MloF + ((ks * 4 + m) * 64 + lane) * 8);
      acc[m] = __builtin_amdgcn_mfma_f32_16x16x32_bf16(ah, bb, acc[m], 0, 0, 0);
      acc[m] = __builtin_amdgcn_mfma_f32_16x16x32_bf16(al, bb, acc[m], 0, 0, 0);
    }
  }

  // D: col(lane&15)=pos, row=(lane>>4)*4+r = c within m-tile
  float* up = U + (size_t)(pos0 + lr) * 64;
  #pragma unroll
  for (int m = 0; m < 4; ++m)
    #pragma unroll
    for (int r = 0; r < 4; ++r)
      up[m * 16 + q * 4 + r] = acc[m][r];
}

// ---------------------------------------------------------------------------
// Kernel C v5: fused attention, single-pass online (no-max; |s|<~10 safe).
// wave = 4 positions (rows of 16 lanes); lane owns channels 4*(lane&15)+0..3.
// Per tap: 1 bf16x4 load, 4 FMA, 3 adds, 4 row-ror DPP adds, exp, PV FMAs.
// grid = 2048 x 256.
// ---------------------------------------------------------------------------
__global__ __launch_bounds__(256) void attn_kernel(
    const u16* __restrict__ xbt, const float* __restrict__ U,
    const float* __restrict__ wpos, u16* __restrict__ GB) {
  int wave = threadIdx.x >> 6, lane = threadIdx.x & 63;
  int lr = lane & 15, row = lane >> 4;
  int pos = blockIdx.x * 16 + wave * 4 + row;
  int b = pos >> 12, ho = (pos >> 6) & 63, wo = pos & 63;
  int y0 = 2 * ho, x0 = 2 * wo;
  const u16* xb = xbt + (size_t)b * (H_ * W_ * 64);

  f4 u = *reinterpret_cast<const f4*>(U + (size_t)pos * 64 + lr * 4);

  bool mn = (wo > 0), mp = (wo < 63);

  float Z = 0.f;
  float g0[4] = {0.f, 0.f, 0.f, 0.f}, g1[4] = {0.f, 0.f, 0.f, 0.f};

  #pragma unroll
  for (int dy = -2; dy <= 2; ++dy) {
    int y = y0 + dy;
    if ((unsigned)y < (unsigned)H_) {     // wave-uniform branch
      const u16* xrow = xb + (size_t)y * (W_ * 64);
      #pragma unroll
      for (int dx = -2; dx <= 2; ++dx) {
        const int p = (dy + 2) * 5 + (dx + 2);
        int xw = x0 + dx;
        int xwc = min(max(xw, 0), W_ - 1);
        const uint_* src = (const uint_*)(xrow + xwc * 64 + lr * 4);
        uint_ d0 = src[0], d1 = src[1];
        float xv0 = __uint_as_float(d0 << 16);
        float xv1 = __uint_as_float(d0 & 0xffff0000u);
        float xv2 = __uint_as_float(d1 << 16);
        float xv3 = __uint_as_float(d1 & 0xffff0000u);
        float sp = fmaf(u.x, xv0, fmaf(u.y, xv1, fmaf(u.z, xv2, u.w * xv3)));
        sp = dpp_add<0x121>(sp);   // row_ror:1
        sp = dpp_add<0x122>(sp);   // row_ror:2
        sp = dpp_add<0x124>(sp);   // row_ror:4
        sp = dpp_add<0x128>(sp);   // row_ror:8 -> full 64-ch sum per row
        bool v = (dx < 0) ? mn : ((dx == 2) ? mp : true);
        sp = v ? sp : 0.f;         // zero-pad score
        float e = __expf(sp);
        Z += e;                    // invalid taps contribute exp(0)=1
        float c0 = v ? e * wpos[p] : 0.f;
        float c1 = v ? e * wpos[32 + p] : 0.f;
        g0[0] = fmaf(c0, xv0, g0[0]);
        g0[1] = fmaf(c0, xv1, g0[1]);
        g0[2] = fmaf(c0, xv2, g0[2]);
        g0[3] = fmaf(c0, xv3, g0[3]);
        g1[0] = fmaf(c1, xv0, g1[0]);
        g1[1] = fmaf(c1, xv1, g1[1]);
        g1[2] = fmaf(c1, xv2, g1[2]);
        g1[3] = fmaf(c1, xv3, g1[3]);
      }
    } else {
      Z += 5.f;                    // 5 OOB taps x exp(0)
    }
  }
  float rZ = 1.f / Z;

  uint_* gp = (uint_*)(GB + (size_t)pos * 128 + lr * 4);
  gp[0] = pack2bf(g0[0] * rZ, g0[1] * rZ);
  gp[1] = pack2bf(g0[2] * rZ, g0[3] * rZ);
  uint_* gp1 = (uint_*)(GB + (size_t)pos * 128 + 64 + lr * 4);
  gp1[0] = pack2bf(g1[0] * rZ, g1[1] * rZ);
  gp1[1] = pack2bf(g1[2] * rZ, g1[3] * rZ);
}

// ---------------------------------------------------------------------------
// Kernel D (MFMA, unchanged from R4): out[c][pos] = sum_k Wv[c][k] G[pos][k]
// ---------------------------------------------------------------------------
__global__ __launch_bounds__(256) void out_kernel(
    const u16* __restrict__ GB, const u16* __restrict__ WhiF,
    const u16* __restrict__ WloF, float* __restrict__ out) {
  int wave = threadIdx.x >> 6, lane = threadIdx.x & 63;
  int lr = lane & 15, q = lane >> 4;
  int pos0 = blockIdx.x * 128 + wave * 32;

  f4 acc[8][2];
  #pragma unroll
  for (int m = 0; m < 8; ++m) {
    acc[m][0] = (f4)0.f;
    acc[m][1] = (f4)0.f;
  }

  #pragma unroll
  for (int ks = 0; ks < 4; ++ks) {
    bfrag b0 = *reinterpret_cast<const bfrag*>(
        GB + (((size_t)(pos0 + lr)) << 7) + ks * 32 + q * 8);
    bfrag b1 = *reinterpret_cast<const bfrag*>(
        GB + (((size_t)(pos0 + 16 + lr)) << 7) + ks * 32 + q * 8);
    const u16* hbase = WhiF + (ks * 8 * 64 + lane) * 8;
    const u16* lbase = WloF + (ks * 8 * 64 + lane) * 8;
    #pragma unroll
    for (int m = 0; m < 8; ++m) {
      bfrag ah = *reinterpret_cast<const bfrag*>(hbase + m * 512);
      bfrag al = *reinterpret_cast<const bfrag*>(lbase + m * 512);
      acc[m][0] = __builtin_amdgcn_mfma_f32_16x16x32_bf16(ah, b0, acc[m][0], 0, 0, 0);
      acc[m][1] = __builtin_amdgcn_mfma_f32_16x16x32_bf16(ah, b1, acc[m][1], 0, 0, 0);
      acc[m][0] = __builtin_amdgcn_mfma_f32_16x16x32_bf16(al, b0, acc[m][0], 0, 0, 0);
      acc[m][1] = __builtin_amdgcn_mfma_f32_16x16x32_bf16(al, b1, acc[m][1], 0, 0, 0);
    }
  }

  int b = pos0 >> 12;
  int hw = pos0 & 4095;
  float* op = out + (size_t)b * (OC_ * HO_ * WO_) + hw;
  #pragma unroll
  for (int m = 0; m < 8; ++m) {
    #pragma unroll
    for (int r = 0; r < 4; ++r) {
      int c = m * 16 + q * 4 + r;
      op[(size_t)c * 4096 + lr] = acc[m][0][r];
      op[(size_t)c * 4096 + 16 + lr] = acc[m][1][r];
    }
  }
}

// ---------------------------------------------------------------------------
extern "C" void kernel_launch(void* const* d_in, const int* in_sizes, int n_in,
                              void* d_out, int out_size, void* d_ws, size_t ws_size,
                              hipStream_t stream) {
  const float* x       = (const float*)d_in[0];
  const float* w_q     = (const float*)d_in[1];
  const float* w_k     = (const float*)d_in[2];
  const float* w_v     = (const float*)d_in[3];
  const float* row_emb = (const float*)d_in[4];
  const float* col_emb = (const float*)d_in[5];
  const float* mix_emb = (const float*)d_in[6];
  float* out = (float*)d_out;

  float* ws   = (float*)d_ws;
  u16*   xbt  = (u16*)(ws + XBT_OFF);
  float* U    = ws + U_OFF;
  u16*   GB   = (u16*)(ws + GB_OFF);
  u16*   MhiF = (u16*)(ws + MHI_OFF);
  u16*   MloF = (u16*)(ws + MLO_OFF);
  u16*   WhiF = (u16*)(ws + WHI_OFF);
  u16*   WloF = (u16*)(ws + WLO_OFF);
  float* wpos = ws + WPOS_OFF;

  prep_kernel<<<33, 256, 0, stream>>>(w_q, w_k, w_v, row_emb, col_emb, mix_emb,
                                      MhiF, MloF, WhiF, WloF, wpos);
  transpose_kernel<<<B_ * H_, 256, 0, stream>>>(x, xbt);
  u_kernel<<<512, 256, 0, stream>>>(xbt, MhiF, MloF, U);
  attn_kernel<<<NPOS / 16, 256, 0, stream>>>(xbt, U, wpos, GB);
  out_kernel<<<256, 256, 0, stream>>>(GB, WhiF, WloF, out);
}

// Round 6
// 47.939 us; speedup vs baseline: 5.0238x; 1.2210x over previous
//
#include <hip/hip_runtime.h>

typedef unsigned int   uint_;
typedef unsigned short u16;

// Problem constants
#define B_    8
#define CIN_  64
#define H_    128
#define W_    128
#define OC_   128
#define HO_   64
#define WO_   64
#define NPOS  (B_ * HO_ * WO_)   // 32768

// ws layout (float offsets)
#define XBT_OFF  0          // bf16 x_bt (B,H,W,64) = 4194304 floats
#define U_OFF    4194304    // f32 U[NPOS][64]      = 2097152 floats
#define MHI_OFF  6291456    // u16[4096]  = 2048 floats
#define MLO_OFF  6293504
#define WHI_OFF  6295552    // u16[16384] = 8192 floats
#define WLO_OFF  6303744
#define WPOS_OFF 6311936    // wpos0[25] @ +0, wpos1[25] @ +32

// ---------------------------------------------------------------------------
// helpers
// ---------------------------------------------------------------------------
__device__ __forceinline__ u16 f2bf(float x) {          // RNE float->bf16
  uint_ u = __float_as_uint(x);
  u += 0x7FFFu + ((u >> 16) & 1u);
  return (u16)(u >> 16);
}
__device__ __forceinline__ uint_ pack2bf(float lo, float hi) {
  return ((uint_)f2bf(hi) << 16) | (uint_)f2bf(lo);
}

template <int CTRL>
__device__ __forceinline__ float dpp_add(float x) {
  int y = __builtin_amdgcn_update_dpp(0, __float_as_int(x), CTRL, 0xf, 0xf, true);
  return x + __int_as_float(y);
}

typedef __attribute__((ext_vector_type(8))) short bfrag;
typedef __attribute__((ext_vector_type(4))) float f4;

// ---------------------------------------------------------------------------
// Kernel A (prep): M-frags (hi/lo), wpos softmax, Wv-frags (hi/lo).
// grid = 33 x 256. A-frag layout (16x16x32): lane=(i&15)+16*((k>>3)&3), reg=k&7.
// ---------------------------------------------------------------------------
__global__ __launch_bounds__(256) void prep_kernel(
    const float* __restrict__ w_q, const float* __restrict__ w_k,
    const float* __restrict__ w_v,
    const float* __restrict__ row_emb, const float* __restrict__ col_emb,
    const float* __restrict__ mix_emb,
    u16* __restrict__ MhiF, u16* __restrict__ MloF,
    u16* __restrict__ WhiF, u16* __restrict__ WloF,
    float* __restrict__ wpos) {
  if (blockIdx.x < 16) {
    // M[a][c] = sum_o w_q[o,a] * w_k[o,c]  -> A-frag (i=c, k=a), 4 m-tiles
    int idx = blockIdx.x * 256 + threadIdx.x;  // 0..4095
    int a = idx >> 6, c = idx & 63;
    float acc = 0.f;
    #pragma unroll 8
    for (int o = 0; o < 128; ++o)
      acc = fmaf(w_q[o * 64 + a], w_k[o * 64 + c], acc);
    u16 hi = f2bf(acc);
    float hif = __uint_as_float((uint_)hi << 16);
    u16 lo = f2bf(acc - hif);
    int m = c >> 4, lr = c & 15;
    int ks = a >> 5, q = (a >> 3) & 3, jr = a & 7;
    int off = ((ks * 4 + m) * 64 + (lr + 16 * q)) * 8 + jr;
    MhiF[off] = hi;
    MloF[off] = lo;
  } else if (blockIdx.x == 16) {
    int p = threadIdx.x;
    if (p < 25) {
      int i = p / 5, j = p % 5;
      float a0 = 0.f, a1 = 0.f;
      for (int c = 0; c < 128; ++c) {
        float rc = row_emb[c * 5 + i] + col_emb[c * 5 + j];
        a0 = fmaf(rc, mix_emb[c * 2 + 0], a0);
        a1 = fmaf(rc, mix_emb[c * 2 + 1], a1);
      }
      float mx = fmaxf(a0, a1);
      float e0 = __expf(a0 - mx), e1 = __expf(a1 - mx);
      float inv = 1.f / (e0 + e1);
      wpos[p] = e0 * inv;
      wpos[32 + p] = e1 * inv;
    }
  } else {
    // Wv[c][k] = w_v[c*128+k]; A-frag (i=c, k), 8 m-tiles (c=128)
    int t = (blockIdx.x - 17) * 256 + threadIdx.x;  // 0..4095
    #pragma unroll
    for (int e = 0; e < 4; ++e) {
      int elem = t * 4 + e;            // = c*128 + k
      int c = elem >> 7, k = elem & 127;
      float w = w_v[elem];
      u16 hi = f2bf(w);
      float hif = __uint_as_float((uint_)hi << 16);
      u16 lo = f2bf(w - hif);
      int m = c >> 4, lr = c & 15;
      int ks = k >> 5, q = (k >> 3) & 3, j = k & 7;
      int off = ((ks * 8 + m) * 64 + (lr + 16 * q)) * 8 + j;
      WhiF[off] = hi;
      WloF[off] = lo;
    }
  }
}

// ---------------------------------------------------------------------------
// Kernel T: transpose x (B,C,H,W) f32 -> x_bt (B,H,W,C) bf16. grid = B*H x 256
// ---------------------------------------------------------------------------
__global__ __launch_bounds__(256) void transpose_kernel(
    const float* __restrict__ x, u16* __restrict__ xbt) {
  __shared__ float tile[64][129];
  int by = blockIdx.x;
  int b = by >> 7, y = by & 127;
  const float* xp = x + (size_t)b * (CIN_ * H_ * W_) + (size_t)y * W_;
  #pragma unroll
  for (int it = 0; it < 32; ++it) {
    int idx = threadIdx.x + it * 256;
    int c = idx >> 7, xw = idx & 127;
    tile[c][xw] = xp[(size_t)c * (H_ * W_) + xw];
  }
  __syncthreads();
  uint_* dst = (uint_*)(xbt + ((size_t)(b * H_ + y)) * (W_ * 64));
  #pragma unroll
  for (int it = 0; it < 16; ++it) {
    int idx = threadIdx.x + it * 256;   // = xw*32 + cp
    int xw = idx >> 5, cp = idx & 31;
    dst[idx] = pack2bf(tile[2 * cp][xw], tile[2 * cp + 1][xw]);
  }
}

// ---------------------------------------------------------------------------
// Kernel U (MFMA): U[pos][c] = sum_a M[a][c] * xq[pos][a].
// wave = one 16-pos tile. grid = 512 x 256 (4 waves).
// ---------------------------------------------------------------------------
__global__ __launch_bounds__(256) void u_kernel(
    const u16* __restrict__ xbt, const u16* __restrict__ MhiF,
    const u16* __restrict__ MloF, float* __restrict__ U) {
  int wave = threadIdx.x >> 6, lane = threadIdx.x & 63;
  int lr = lane & 15, q = lane >> 4;
  int tile = blockIdx.x * 4 + wave;   // 0..2047
  int pos0 = tile * 16;
  int pos = pos0 + lr;                // B-frag col j = lr
  int b = pos >> 12, ho = (pos >> 6) & 63, wo = pos & 63;
  const u16* xq = xbt + ((size_t)(b * H_ + 2 * ho) * W_ + 2 * wo) * 64;

  f4 acc[4];
  #pragma unroll
  for (int m = 0; m < 4; ++m) acc[m] = (f4)0.f;

  #pragma unroll
  for (int ks = 0; ks < 2; ++ks) {
    bfrag bb = *reinterpret_cast<const bfrag*>(xq + ks * 32 + q * 8);
    #pragma unroll
    for (int m = 0; m < 4; ++m) {
      bfrag ah = *reinterpret_cast<const bfrag*>(MhiF + ((ks * 4 + m) * 64 + lane) * 8);
      bfrag al = *reinterpret_cast<const bfrag*>(MloF + ((ks * 4 + m) * 64 + lane) * 8);
      acc[m] = __builtin_amdgcn_mfma_f32_16x16x32_bf16(ah, bb, acc[m], 0, 0, 0);
      acc[m] = __builtin_amdgcn_mfma_f32_16x16x32_bf16(al, bb, acc[m], 0, 0, 0);
    }
  }

  float* up = U + (size_t)(pos0 + lr) * 64;
  #pragma unroll
  for (int m = 0; m < 4; ++m)
    #pragma unroll
    for (int r = 0; r < 4; ++r)
      up[m * 16 + q * 4 + r] = acc[m][r];
}

// ---------------------------------------------------------------------------
// Kernel CD (fused attn + out GEMM). Block = 512 threads (8 waves) = 32 pos.
// Phase 1: wave w computes G for positions pos0+4w..+3 (lane = 16ch x 4pos,
//          DPP row-16 reduce, online softmax) -> LDS Gl[32][136] (padded).
// Phase 2: wave w = m-tile (ch 16w..16w+15); B-frags ds_read from Gl;
//          A-frags (Wv hi/lo) from global (L2-hot); 16 MFMA; store out.
// grid = NPOS/32 = 1024.
// ---------------------------------------------------------------------------
__global__ __launch_bounds__(512) void attn_out_kernel(
    const u16* __restrict__ xbt, const float* __restrict__ U,
    const float* __restrict__ wpos, const u16* __restrict__ WhiF,
    const u16* __restrict__ WloF, float* __restrict__ out) {
  __shared__ u16 Gl[32][136];   // row stride 272 B: banks 4r+2lr -> <=2-way

  int wave = threadIdx.x >> 6, lane = threadIdx.x & 63;
  int lr = lane & 15, q = lane >> 4;
  int pos0 = blockIdx.x * 32;

  // ----- Phase 1: attention -----
  {
    int r = wave * 4 + q;              // row in Gl, 0..31
    int pos = pos0 + r;
    int b = pos >> 12, ho = (pos >> 6) & 63, wo = pos & 63;
    int y0 = 2 * ho, x0 = 2 * wo;
    const u16* xb = xbt + (size_t)b * (H_ * W_ * 64);

    f4 u = *reinterpret_cast<const f4*>(U + (size_t)pos * 64 + lr * 4);
    bool mn = (wo > 0), mp = (wo < 63);

    float Z = 0.f;
    float g0[4] = {0.f, 0.f, 0.f, 0.f}, g1[4] = {0.f, 0.f, 0.f, 0.f};

    #pragma unroll
    for (int dy = -2; dy <= 2; ++dy) {
      int y = y0 + dy;
      if ((unsigned)y < (unsigned)H_) {   // wave-uniform (4 pos share ho)
        const u16* xrow = xb + (size_t)y * (W_ * 64);
        #pragma unroll
        for (int dx = -2; dx <= 2; ++dx) {
          const int p = (dy + 2) * 5 + (dx + 2);
          int xw = x0 + dx;
          int xwc = min(max(xw, 0), W_ - 1);
          uint2 d = *(const uint2*)(xrow + xwc * 64 + lr * 4);
          float xv0 = __uint_as_float(d.x << 16);
          float xv1 = __uint_as_float(d.x & 0xffff0000u);
          float xv2 = __uint_as_float(d.y << 16);
          float xv3 = __uint_as_float(d.y & 0xffff0000u);
          float sp = fmaf(u.x, xv0, fmaf(u.y, xv1, fmaf(u.z, xv2, u.w * xv3)));
          sp = dpp_add<0x121>(sp);   // row_ror:1
          sp = dpp_add<0x122>(sp);   // row_ror:2
          sp = dpp_add<0x124>(sp);   // row_ror:4
          sp = dpp_add<0x128>(sp);   // row_ror:8 -> full 64-ch sum per row
          bool v = (dx < 0) ? mn : ((dx == 2) ? mp : true);
          sp = v ? sp : 0.f;
          float e = __expf(sp);
          Z += e;
          float c0 = v ? e * wpos[p] : 0.f;
          float c1 = v ? e * wpos[32 + p] : 0.f;
          g0[0] = fmaf(c0, xv0, g0[0]);
          g0[1] = fmaf(c0, xv1, g0[1]);
          g0[2] = fmaf(c0, xv2, g0[2]);
          g0[3] = fmaf(c0, xv3, g0[3]);
          g1[0] = fmaf(c1, xv0, g1[0]);
          g1[1] = fmaf(c1, xv1, g1[1]);
          g1[2] = fmaf(c1, xv2, g1[2]);
          g1[3] = fmaf(c1, xv3, g1[3]);
        }
      } else {
        Z += 5.f;
      }
    }
    float rZ = 1.f / Z;

    uint2 w0, w1;
    w0.x = pack2bf(g0[0] * rZ, g0[1] * rZ);
    w0.y = pack2bf(g0[2] * rZ, g0[3] * rZ);
    w1.x = pack2bf(g1[0] * rZ, g1[1] * rZ);
    w1.y = pack2bf(g1[2] * rZ, g1[3] * rZ);
    *(uint2*)&Gl[r][lr * 4] = w0;
    *(uint2*)&Gl[r][64 + lr * 4] = w1;
  }

  __syncthreads();

  // ----- Phase 2: out GEMM (wave = m-tile, validated fragment conventions) --
  {
    f4 acc0 = (f4)0.f, acc1 = (f4)0.f;
    #pragma unroll
    for (int ks = 0; ks < 4; ++ks) {
      bfrag b0 = *reinterpret_cast<const bfrag*>(&Gl[lr][ks * 32 + q * 8]);
      bfrag b1 = *reinterpret_cast<const bfrag*>(&Gl[16 + lr][ks * 32 + q * 8]);
      bfrag ah = *reinterpret_cast<const bfrag*>(
          WhiF + ((ks * 8 + wave) * 64 + lane) * 8);
      bfrag al = *reinterpret_cast<const bfrag*>(
          WloF + ((ks * 8 + wave) * 64 + lane) * 8);
      acc0 = __builtin_amdgcn_mfma_f32_16x16x32_bf16(ah, b0, acc0, 0, 0, 0);
      acc1 = __builtin_amdgcn_mfma_f32_16x16x32_bf16(ah, b1, acc1, 0, 0, 0);
      acc0 = __builtin_amdgcn_mfma_f32_16x16x32_bf16(al, b0, acc0, 0, 0, 0);
      acc1 = __builtin_amdgcn_mfma_f32_16x16x32_bf16(al, b1, acc1, 0, 0, 0);
    }
    int b = pos0 >> 12;
    int hw0 = pos0 & 4095;
    float* op = out + (size_t)b * (OC_ * HO_ * WO_) + hw0;
    #pragma unroll
    for (int rr = 0; rr < 4; ++rr) {
      int c = wave * 16 + q * 4 + rr;
      op[(size_t)c * 4096 + lr] = acc0[rr];
      op[(size_t)c * 4096 + 16 + lr] = acc1[rr];
    }
  }
}

// ---------------------------------------------------------------------------
extern "C" void kernel_launch(void* const* d_in, const int* in_sizes, int n_in,
                              void* d_out, int out_size, void* d_ws, size_t ws_size,
                              hipStream_t stream) {
  const float* x       = (const float*)d_in[0];
  const float* w_q     = (const float*)d_in[1];
  const float* w_k     = (const float*)d_in[2];
  const float* w_v     = (const float*)d_in[3];
  const float* row_emb = (const float*)d_in[4];
  const float* col_emb = (const float*)d_in[5];
  const float* mix_emb = (const float*)d_in[6];
  float* out = (float*)d_out;

  float* ws   = (float*)d_ws;
  u16*   xbt  = (u16*)(ws + XBT_OFF);
  float* U    = ws + U_OFF;
  u16*   MhiF = (u16*)(ws + MHI_OFF);
  u16*   MloF = (u16*)(ws + MLO_OFF);
  u16*   WhiF = (u16*)(ws + WHI_OFF);
  u16*   WloF = (u16*)(ws + WLO_OFF);
  float* wpos = ws + WPOS_OFF;

  prep_kernel<<<33, 256, 0, stream>>>(w_q, w_k, w_v, row_emb, col_emb, mix_emb,
                                      MhiF, MloF, WhiF, WloF, wpos);
  transpose_kernel<<<B_ * H_, 256, 0, stream>>>(x, xbt);
  u_kernel<<<512, 256, 0, stream>>>(xbt, MhiF, MloF, U);
  attn_out_kernel<<<NPOS / 32, 512, 0, stream>>>(xbt, U, wpos, WhiF, WloF, out);
}

// Round 7
// 42.482 us; speedup vs baseline: 5.6691x; 1.1285x over previous
//
#include <hip/hip_runtime.h>

typedef unsigned int   uint_;
typedef unsigned short u16;

// Problem constants
#define B_    8
#define CIN_  64
#define H_    128
#define W_    128
#define OC_   128
#define HO_   64
#define WO_   64
#define NPOS  (B_ * HO_ * WO_)   // 32768

// ws layout (float offsets)
#define XBT_OFF  0          // bf16 x_bt (B,H,W,64) = 4194304 floats
#define MHI_OFF  4194304    // u16[4096]  = 2048 floats
#define MLO_OFF  4196352
#define WHI_OFF  4198400    // u16[16384] = 8192 floats
#define WLO_OFF  4206592
#define WPOS_OFF 4214784    // wpos0[25] @ +0, wpos1[25] @ +32

// ---------------------------------------------------------------------------
// helpers
// ---------------------------------------------------------------------------
__device__ __forceinline__ u16 f2bf(float x) {          // RNE float->bf16
  uint_ u = __float_as_uint(x);
  u += 0x7FFFu + ((u >> 16) & 1u);
  return (u16)(u >> 16);
}
__device__ __forceinline__ uint_ pack2bf(float lo, float hi) {
  return ((uint_)f2bf(hi) << 16) | (uint_)f2bf(lo);
}

template <int CTRL>
__device__ __forceinline__ float dpp_add(float x) {
  int y = __builtin_amdgcn_update_dpp(0, __float_as_int(x), CTRL, 0xf, 0xf, true);
  return x + __int_as_float(y);
}

typedef __attribute__((ext_vector_type(8))) short bfrag;
typedef __attribute__((ext_vector_type(4))) float f4;

// ---------------------------------------------------------------------------
// Dispatch 1 (mega): blocks 0..1023 = transpose x f32 -> xbt bf16;
// blocks 1024..1056 = prep (M-frags, wpos, Wv-frags). Independent work,
// outputs consumed only in dispatch 2.
// A-frag layout (16x16x32): lane=(i&15)+16*((k>>3)&3), reg=k&7.
// ---------------------------------------------------------------------------
__global__ __launch_bounds__(256) void mega_kernel(
    const float* __restrict__ x, u16* __restrict__ xbt,
    const float* __restrict__ w_q, const float* __restrict__ w_k,
    const float* __restrict__ w_v,
    const float* __restrict__ row_emb, const float* __restrict__ col_emb,
    const float* __restrict__ mix_emb,
    u16* __restrict__ MhiF, u16* __restrict__ MloF,
    u16* __restrict__ WhiF, u16* __restrict__ WloF,
    float* __restrict__ wpos) {
  if (blockIdx.x < 1024) {
    // ---- transpose one (b,y) row: x (B,C,H,W) -> xbt (B,H,W,C) bf16 ----
    __shared__ float tile[64][129];
    int by = blockIdx.x;
    int b = by >> 7, y = by & 127;
    const float* xp = x + (size_t)b * (CIN_ * H_ * W_) + (size_t)y * W_;
    #pragma unroll
    for (int it = 0; it < 32; ++it) {
      int idx = threadIdx.x + it * 256;
      int c = idx >> 7, xw = idx & 127;
      tile[c][xw] = xp[(size_t)c * (H_ * W_) + xw];
    }
    __syncthreads();
    uint_* dst = (uint_*)(xbt + ((size_t)(b * H_ + y)) * (W_ * 64));
    #pragma unroll
    for (int it = 0; it < 16; ++it) {
      int idx = threadIdx.x + it * 256;   // = xw*32 + cp
      int xw = idx >> 5, cp = idx & 31;
      dst[idx] = pack2bf(tile[2 * cp][xw], tile[2 * cp + 1][xw]);
    }
  } else {
    int pb = blockIdx.x - 1024;   // 0..32
    if (pb < 16) {
      // M[a][c] = sum_o w_q[o,a] * w_k[o,c]  -> A-frag (i=c, k=a), 4 m-tiles
      int idx = pb * 256 + threadIdx.x;  // 0..4095
      int a = idx >> 6, c = idx & 63;
      float acc = 0.f;
      #pragma unroll 8
      for (int o = 0; o < 128; ++o)
        acc = fmaf(w_q[o * 64 + a], w_k[o * 64 + c], acc);
      u16 hi = f2bf(acc);
      float hif = __uint_as_float((uint_)hi << 16);
      u16 lo = f2bf(acc - hif);
      int m = c >> 4, lr = c & 15;
      int ks = a >> 5, q = (a >> 3) & 3, jr = a & 7;
      int off = ((ks * 4 + m) * 64 + (lr + 16 * q)) * 8 + jr;
      MhiF[off] = hi;
      MloF[off] = lo;
    } else if (pb == 16) {
      int p = threadIdx.x;
      if (p < 25) {
        int i = p / 5, j = p % 5;
        float a0 = 0.f, a1 = 0.f;
        for (int c = 0; c < 128; ++c) {
          float rc = row_emb[c * 5 + i] + col_emb[c * 5 + j];
          a0 = fmaf(rc, mix_emb[c * 2 + 0], a0);
          a1 = fmaf(rc, mix_emb[c * 2 + 1], a1);
        }
        float mx = fmaxf(a0, a1);
        float e0 = __expf(a0 - mx), e1 = __expf(a1 - mx);
        float inv = 1.f / (e0 + e1);
        wpos[p] = e0 * inv;
        wpos[32 + p] = e1 * inv;
      }
    } else {
      // Wv[c][k] = w_v[c*128+k]; A-frag (i=c, k), 8 m-tiles (c=128)
      int t = (pb - 17) * 256 + threadIdx.x;  // 0..4095
      #pragma unroll
      for (int e = 0; e < 4; ++e) {
        int elem = t * 4 + e;            // = c*128 + k
        int c = elem >> 7, k = elem & 127;
        float w = w_v[elem];
        u16 hi = f2bf(w);
        float hif = __uint_as_float((uint_)hi << 16);
        u16 lo = f2bf(w - hif);
        int m = c >> 4, lr = c & 15;
        int ks = k >> 5, q = (k >> 3) & 3, j = k & 7;
        int off = ((ks * 8 + m) * 64 + (lr + 16 * q)) * 8 + j;
        WhiF[off] = hi;
        WloF[off] = lo;
      }
    }
  }
}

// ---------------------------------------------------------------------------
// Dispatch 2 (fused U + attn + out GEMM). Block = 512 threads (8 waves)
// = 32 positions (one half-row: same b, same ho).
// Phase 0: U[32 pos][64 ch] via MFMA (wave = (pos-tile, m-tile)) -> LDS Ul.
// Phase 1: attention (lane = 16ch x 4pos, DPP row-16 reduce, online
//          softmax, no-max) -> LDS Gl[32][136] bf16 (padded).
// Phase 2: out GEMM: wave = m-tile; B-frags ds_read from Gl; A-frags
//          (Wv hi/lo) L2-hot; 16 MFMA; coalesced store.
// grid = NPOS/32 = 1024.
// ---------------------------------------------------------------------------
__global__ __launch_bounds__(512) void attn_out_kernel(
    const u16* __restrict__ xbt, const u16* __restrict__ MhiF,
    const u16* __restrict__ MloF, const float* __restrict__ wpos,
    const u16* __restrict__ WhiF, const u16* __restrict__ WloF,
    float* __restrict__ out) {
  __shared__ u16 Gl[32][136];   // row stride 272 B
  __shared__ float Ul[32][68];  // row stride 272 B

  int wave = threadIdx.x >> 6, lane = threadIdx.x & 63;
  int lr = lane & 15, q = lane >> 4;
  int pos0 = blockIdx.x * 32;

  // ----- Phase 0: U = M^T xq for the block's 32 positions -----
  {
    int pt = wave >> 2, mm = wave & 3;      // pos-tile (0,1), m-tile (0..3)
    int pu = pos0 + pt * 16 + lr;           // B-frag col j = lr
    int bu = pu >> 12, hou = (pu >> 6) & 63, wou = pu & 63;
    const u16* xq = xbt + ((size_t)(bu * H_ + 2 * hou) * W_ + 2 * wou) * 64;
    f4 ua = (f4)0.f;
    #pragma unroll
    for (int ks = 0; ks < 2; ++ks) {
      bfrag bb = *reinterpret_cast<const bfrag*>(xq + ks * 32 + q * 8);
      bfrag ah = *reinterpret_cast<const bfrag*>(
          MhiF + ((ks * 4 + mm) * 64 + lane) * 8);
      bfrag al = *reinterpret_cast<const bfrag*>(
          MloF + ((ks * 4 + mm) * 64 + lane) * 8);
      ua = __builtin_amdgcn_mfma_f32_16x16x32_bf16(ah, bb, ua, 0, 0, 0);
      ua = __builtin_amdgcn_mfma_f32_16x16x32_bf16(al, bb, ua, 0, 0, 0);
    }
    // D: col(lane&15)=pos, row=(lane>>4)*4+r = ch within m-tile
    #pragma unroll
    for (int r = 0; r < 4; ++r)
      Ul[pt * 16 + lr][mm * 16 + q * 4 + r] = ua[r];
  }
  __syncthreads();

  // ----- Phase 1: attention -----
  {
    int r = wave * 4 + q;              // row in Gl, 0..31
    int pos = pos0 + r;
    int b = pos >> 12, ho = (pos >> 6) & 63, wo = pos & 63;
    int y0 = 2 * ho, x0 = 2 * wo;
    const u16* xb = xbt + (size_t)b * (H_ * W_ * 64);

    f4 u = *reinterpret_cast<const f4*>(&Ul[r][lr * 4]);
    bool mn = (wo > 0), mp = (wo < 63);

    float Z = 0.f;
    float g0[4] = {0.f, 0.f, 0.f, 0.f}, g1[4] = {0.f, 0.f, 0.f, 0.f};

    #pragma unroll
    for (int dy = -2; dy <= 2; ++dy) {
      int y = y0 + dy;
      if ((unsigned)y < (unsigned)H_) {   // wave-uniform (4 pos share ho)
        const u16* xrow = xb + (size_t)y * (W_ * 64);
        #pragma unroll
        for (int dx = -2; dx <= 2; ++dx) {
          const int p = (dy + 2) * 5 + (dx + 2);
          int xw = x0 + dx;
          int xwc = min(max(xw, 0), W_ - 1);
          uint2 d = *(const uint2*)(xrow + xwc * 64 + lr * 4);
          float xv0 = __uint_as_float(d.x << 16);
          float xv1 = __uint_as_float(d.x & 0xffff0000u);
          float xv2 = __uint_as_float(d.y << 16);
          float xv3 = __uint_as_float(d.y & 0xffff0000u);
          float sp = fmaf(u.x, xv0, fmaf(u.y, xv1, fmaf(u.z, xv2, u.w * xv3)));
          sp = dpp_add<0x121>(sp);   // row_ror:1
          sp = dpp_add<0x122>(sp);   // row_ror:2
          sp = dpp_add<0x124>(sp);   // row_ror:4
          sp = dpp_add<0x128>(sp);   // row_ror:8 -> full 64-ch sum per row
          bool v = (dx < 0) ? mn : ((dx == 2) ? mp : true);
          sp = v ? sp : 0.f;
          float e = __expf(sp);
          Z += e;
          float c0 = v ? e * wpos[p] : 0.f;
          float c1 = v ? e * wpos[32 + p] : 0.f;
          g0[0] = fmaf(c0, xv0, g0[0]);
          g0[1] = fmaf(c0, xv1, g0[1]);
          g0[2] = fmaf(c0, xv2, g0[2]);
          g0[3] = fmaf(c0, xv3, g0[3]);
          g1[0] = fmaf(c1, xv0, g1[0]);
          g1[1] = fmaf(c1, xv1, g1[1]);
          g1[2] = fmaf(c1, xv2, g1[2]);
          g1[3] = fmaf(c1, xv3, g1[3]);
        }
      } else {
        Z += 5.f;
      }
    }
    float rZ = 1.f / Z;

    uint2 w0, w1;
    w0.x = pack2bf(g0[0] * rZ, g0[1] * rZ);
    w0.y = pack2bf(g0[2] * rZ, g0[3] * rZ);
    w1.x = pack2bf(g1[0] * rZ, g1[1] * rZ);
    w1.y = pack2bf(g1[2] * rZ, g1[3] * rZ);
    *(uint2*)&Gl[r][lr * 4] = w0;
    *(uint2*)&Gl[r][64 + lr * 4] = w1;
  }

  __syncthreads();

  // ----- Phase 2: out GEMM (wave = m-tile; validated fragment conventions) --
  {
    f4 acc0 = (f4)0.f, acc1 = (f4)0.f;
    #pragma unroll
    for (int ks = 0; ks < 4; ++ks) {
      bfrag b0 = *reinterpret_cast<const bfrag*>(&Gl[lr][ks * 32 + q * 8]);
      bfrag b1 = *reinterpret_cast<const bfrag*>(&Gl[16 + lr][ks * 32 + q * 8]);
      bfrag ah = *reinterpret_cast<const bfrag*>(
          WhiF + ((ks * 8 + wave) * 64 + lane) * 8);
      bfrag al = *reinterpret_cast<const bfrag*>(
          WloF + ((ks * 8 + wave) * 64 + lane) * 8);
      acc0 = __builtin_amdgcn_mfma_f32_16x16x32_bf16(ah, b0, acc0, 0, 0, 0);
      acc1 = __builtin_amdgcn_mfma_f32_16x16x32_bf16(ah, b1, acc1, 0, 0, 0);
      acc0 = __builtin_amdgcn_mfma_f32_16x16x32_bf16(al, b0, acc0, 0, 0, 0);
      acc1 = __builtin_amdgcn_mfma_f32_16x16x32_bf16(al, b1, acc1, 0, 0, 0);
    }
    int b = pos0 >> 12;
    int hw0 = pos0 & 4095;
    float* op = out + (size_t)b * (OC_ * HO_ * WO_) + hw0;
    #pragma unroll
    for (int rr = 0; rr < 4; ++rr) {
      int c = wave * 16 + q * 4 + rr;
      op[(size_t)c * 4096 + lr] = acc0[rr];
      op[(size_t)c * 4096 + 16 + lr] = acc1[rr];
    }
  }
}

// ---------------------------------------------------------------------------
extern "C" void kernel_launch(void* const* d_in, const int* in_sizes, int n_in,
                              void* d_out, int out_size, void* d_ws, size_t ws_size,
                              hipStream_t stream) {
  const float* x       = (const float*)d_in[0];
  const float* w_q     = (const float*)d_in[1];
  const float* w_k     = (const float*)d_in[2];
  const float* w_v     = (const float*)d_in[3];
  const float* row_emb = (const float*)d_in[4];
  const float* col_emb = (const float*)d_in[5];
  const float* mix_emb = (const float*)d_in[6];
  float* out = (float*)d_out;

  float* ws   = (float*)d_ws;
  u16*   xbt  = (u16*)(ws + XBT_OFF);
  u16*   MhiF = (u16*)(ws + MHI_OFF);
  u16*   MloF = (u16*)(ws + MLO_OFF);
  u16*   WhiF = (u16*)(ws + WHI_OFF);
  u16*   WloF = (u16*)(ws + WLO_OFF);
  float* wpos = ws + WPOS_OFF;

  mega_kernel<<<1024 + 33, 256, 0, stream>>>(x, xbt, w_q, w_k, w_v, row_emb,
                                             col_emb, mix_emb, MhiF, MloF,
                                             WhiF, WloF, wpos);
  attn_out_kernel<<<NPOS / 32, 512, 0, stream>>>(xbt, MhiF, MloF, wpos,
                                                 WhiF, WloF, out);
}

// Round 8
// 39.637 us; speedup vs baseline: 6.0760x; 1.0718x over previous
//
#include <hip/hip_runtime.h>

typedef unsigned int   uint_;
typedef unsigned short u16;

// Problem constants
#define B_    8
#define CIN_  64
#define H_    128
#define W_    128
#define OC_   128
#define HO_   64
#define WO_   64
#define NPOS  (B_ * HO_ * WO_)   // 32768

// ws layout (float offsets)
#define XBT_OFF  0          // bf16 x_bt (B,H,W,64) = 4194304 floats
#define MHI_OFF  4194304    // u16[4096]  = 2048 floats
#define MLO_OFF  4196352
#define WHI_OFF  4198400    // u16[16384] = 8192 floats
#define WLO_OFF  4206592
#define WPOS_OFF 4214784    // wpos0[25] @ +0, wpos1[25] @ +32

// ---------------------------------------------------------------------------
// helpers
// ---------------------------------------------------------------------------
__device__ __forceinline__ u16 f2bf(float x) {          // RNE float->bf16
  uint_ u = __float_as_uint(x);
  u += 0x7FFFu + ((u >> 16) & 1u);
  return (u16)(u >> 16);
}
__device__ __forceinline__ uint_ pack2bf(float lo, float hi) {
  return ((uint_)f2bf(hi) << 16) | (uint_)f2bf(lo);
}

template <int CTRL>
__device__ __forceinline__ float dpp_add(float x) {
  int y = __builtin_amdgcn_update_dpp(0, __float_as_int(x), CTRL, 0xf, 0xf, true);
  return x + __int_as_float(y);
}

typedef __attribute__((ext_vector_type(8))) short bfrag;
typedef __attribute__((ext_vector_type(4))) float f4;

// ---------------------------------------------------------------------------
// Dispatch 1 (mega): blocks 0..1023 = transpose x f32 -> xbt bf16;
// blocks 1024..1056 = prep (M-frags, wpos, Wv-frags).
// A-frag layout (16x16x32): lane=(i&15)+16*((k>>3)&3), reg=k&7.
// ---------------------------------------------------------------------------
__global__ __launch_bounds__(256) void mega_kernel(
    const float* __restrict__ x, u16* __restrict__ xbt,
    const float* __restrict__ w_q, const float* __restrict__ w_k,
    const float* __restrict__ w_v,
    const float* __restrict__ row_emb, const float* __restrict__ col_emb,
    const float* __restrict__ mix_emb,
    u16* __restrict__ MhiF, u16* __restrict__ MloF,
    u16* __restrict__ WhiF, u16* __restrict__ WloF,
    float* __restrict__ wpos) {
  if (blockIdx.x < 1024) {
    __shared__ float tile[64][129];
    int by = blockIdx.x;
    int b = by >> 7, y = by & 127;
    const float* xp = x + (size_t)b * (CIN_ * H_ * W_) + (size_t)y * W_;
    #pragma unroll
    for (int it = 0; it < 32; ++it) {
      int idx = threadIdx.x + it * 256;
      int c = idx >> 7, xw = idx & 127;
      tile[c][xw] = xp[(size_t)c * (H_ * W_) + xw];
    }
    __syncthreads();
    uint_* dst = (uint_*)(xbt + ((size_t)(b * H_ + y)) * (W_ * 64));
    #pragma unroll
    for (int it = 0; it < 16; ++it) {
      int idx = threadIdx.x + it * 256;   // = xw*32 + cp
      int xw = idx >> 5, cp = idx & 31;
      dst[idx] = pack2bf(tile[2 * cp][xw], tile[2 * cp + 1][xw]);
    }
  } else {
    int pb = blockIdx.x - 1024;   // 0..32
    if (pb < 16) {
      // M[a][c] = sum_o w_q[o,a] * w_k[o,c]  -> A-frag (i=c, k=a), 4 m-tiles
      int idx = pb * 256 + threadIdx.x;  // 0..4095
      int a = idx >> 6, c = idx & 63;
      float acc = 0.f;
      #pragma unroll 8
      for (int o = 0; o < 128; ++o)
        acc = fmaf(w_q[o * 64 + a], w_k[o * 64 + c], acc);
      u16 hi = f2bf(acc);
      float hif = __uint_as_float((uint_)hi << 16);
      u16 lo = f2bf(acc - hif);
      int m = c >> 4, lr = c & 15;
      int ks = a >> 5, q = (a >> 3) & 3, jr = a & 7;
      int off = ((ks * 4 + m) * 64 + (lr + 16 * q)) * 8 + jr;
      MhiF[off] = hi;
      MloF[off] = lo;
    } else if (pb == 16) {
      int p = threadIdx.x;
      if (p < 25) {
        int i = p / 5, j = p % 5;
        float a0 = 0.f, a1 = 0.f;
        for (int c = 0; c < 128; ++c) {
          float rc = row_emb[c * 5 + i] + col_emb[c * 5 + j];
          a0 = fmaf(rc, mix_emb[c * 2 + 0], a0);
          a1 = fmaf(rc, mix_emb[c * 2 + 1], a1);
        }
        float mx = fmaxf(a0, a1);
        float e0 = __expf(a0 - mx), e1 = __expf(a1 - mx);
        float inv = 1.f / (e0 + e1);
        wpos[p] = e0 * inv;
        wpos[32 + p] = e1 * inv;
      }
    } else {
      // Wv[c][k] = w_v[c*128+k]; A-frag (i=c, k), 8 m-tiles (c=128)
      int t = (pb - 17) * 256 + threadIdx.x;  // 0..4095
      #pragma unroll
      for (int e = 0; e < 4; ++e) {
        int elem = t * 4 + e;            // = c*128 + k
        int c = elem >> 7, k = elem & 127;
        float w = w_v[elem];
        u16 hi = f2bf(w);
        float hif = __uint_as_float((uint_)hi << 16);
        u16 lo = f2bf(w - hif);
        int m = c >> 4, lr = c & 15;
        int ks = k >> 5, q = (k >> 3) & 3, j = k & 7;
        int off = ((ks * 8 + m) * 64 + (lr + 16 * q)) * 8 + j;
        WhiF[off] = hi;
        WloF[off] = lo;
      }
    }
  }
}

// ---------------------------------------------------------------------------
// Dispatch 2 (fused stage + U + attn + out GEMM). 512 thr (8 waves) = 32 pos
// (one half-row: same b, ho). LDS: Xl window 45.6K + Gl 8.7K + Ul 8.7K = 63K.
// Stage:  5 rows x 67 cols x 64ch bf16 window -> Xl (coalesced, 11 iters).
// Phase 0 (same barrier region): U = M^T xq via MFMA -> Ul.
// Phase 1: taps via ds_read_b64 at base+imm (row 9112B, col 136B); DPP
//          row-16 reduce; online softmax (no-max); -> Gl bf16.
// Phase 2: out GEMM (wave = m-tile, Wv hi/lo A-frags, B-frags from Gl).
// grid = NPOS/32 = 1024.
// ---------------------------------------------------------------------------
__global__ __launch_bounds__(512, 4) void attn_out_kernel(
    const u16* __restrict__ xbt, const u16* __restrict__ MhiF,
    const u16* __restrict__ MloF, const float* __restrict__ wpos,
    const u16* __restrict__ WhiF, const u16* __restrict__ WloF,
    float* __restrict__ out) {
  __shared__ u16 Xl[5 * 67 * 68];   // [row][col][ch] ch-stride 68 u16 = 136 B
  __shared__ u16 Gl[32][136];       // row stride 272 B
  __shared__ float Ul[32][68];      // row stride 272 B (16B-aligned rows)

  int tid = threadIdx.x;
  int wave = tid >> 6, lane = tid & 63;
  int lr = lane & 15, q = lane >> 4;
  int pos0 = blockIdx.x * 32;
  int b = pos0 >> 12;
  int ho0 = (pos0 >> 6) & 63;       // shared by all 32 positions
  int wo0 = pos0 & 63;              // 0 or 32
  int y0 = 2 * ho0, x0base = 2 * wo0;

  // ----- Stage x-window -> Xl (5 x 67 col-vectors of 64ch, clamped) -----
  {
    int sl = tid & 15;              // 8-byte ch-chunk within a col-vector
    int pi0 = tid >> 4;             // col-vector index step 32
    const u16* xbb = xbt + (size_t)b * (H_ * W_ * 64);
    #pragma unroll
    for (int it = 0; it < 11; ++it) {
      int pi = it * 32 + pi0;       // 0..351, need 0..334
      if (pi < 335) {
        int row = pi / 67;          // magic-mul
        int col = pi - row * 67;
        int yc = min(max(y0 + row - 2, 0), H_ - 1);
        int xc = min(max(x0base + col - 2, 0), W_ - 1);
        uint2 d = *(const uint2*)(xbb + ((size_t)yc * W_ + xc) * 64 + sl * 4);
        *(uint2*)(&Xl[(row * 67 + col) * 68 + sl * 4]) = d;
      }
    }
  }

  // ----- Phase 0: U = M^T xq for the block's 32 positions (overlaps stage) --
  {
    int pt = wave >> 2, mm = wave & 3;      // pos-tile (0,1), m-tile (0..3)
    int pu = pos0 + pt * 16 + lr;           // B-frag col j = lr
    int bu = pu >> 12, hou = (pu >> 6) & 63, wou = pu & 63;
    const u16* xq = xbt + ((size_t)(bu * H_ + 2 * hou) * W_ + 2 * wou) * 64;
    f4 ua = (f4)0.f;
    #pragma unroll
    for (int ks = 0; ks < 2; ++ks) {
      bfrag bb = *reinterpret_cast<const bfrag*>(xq + ks * 32 + q * 8);
      bfrag ah = *reinterpret_cast<const bfrag*>(
          MhiF + ((ks * 4 + mm) * 64 + lane) * 8);
      bfrag al = *reinterpret_cast<const bfrag*>(
          MloF + ((ks * 4 + mm) * 64 + lane) * 8);
      ua = __builtin_amdgcn_mfma_f32_16x16x32_bf16(ah, bb, ua, 0, 0, 0);
      ua = __builtin_amdgcn_mfma_f32_16x16x32_bf16(al, bb, ua, 0, 0, 0);
    }
    #pragma unroll
    for (int r = 0; r < 4; ++r)
      Ul[pt * 16 + lr][mm * 16 + q * 4 + r] = ua[r];
  }
  __syncthreads();

  // ----- Phase 1: attention from LDS -----
  {
    int r = wave * 4 + q;              // local position 0..31
    int wo = wo0 + r;
    const u16* xl0 = &Xl[(2 * r + 2) * 68 + lr * 4];  // (row0, col 2r+2, ch 4lr)

    f4 u = *reinterpret_cast<const f4*>(&Ul[r][lr * 4]);
    bool mn = (wo > 0), mp = (wo < 63);

    float Z = 0.f;
    float g0[4] = {0.f, 0.f, 0.f, 0.f}, g1[4] = {0.f, 0.f, 0.f, 0.f};

    #pragma unroll
    for (int dy = -2; dy <= 2; ++dy) {
      int y = y0 + dy;
      if ((unsigned)y < (unsigned)H_) {   // block-uniform branch
        #pragma unroll
        for (int dx = -2; dx <= 2; ++dx) {
          const int p = (dy + 2) * 5 + (dx + 2);
          // base + compile-time element offset -> DS imm offset
          uint2 d = *(const uint2*)(xl0 + ((dy + 2) * 67 + dx) * 68);
          float xv0 = __uint_as_float(d.x << 16);
          float xv1 = __uint_as_float(d.x & 0xffff0000u);
          float xv2 = __uint_as_float(d.y << 16);
          float xv3 = __uint_as_float(d.y & 0xffff0000u);
          float sp = fmaf(u.x, xv0, fmaf(u.y, xv1, fmaf(u.z, xv2, u.w * xv3)));
          sp = dpp_add<0x121>(sp);   // row_ror:1
          sp = dpp_add<0x122>(sp);   // row_ror:2
          sp = dpp_add<0x124>(sp);   // row_ror:4
          sp = dpp_add<0x128>(sp);   // row_ror:8 -> full 64-ch sum per row
          bool v = (dx < 0) ? mn : ((dx == 2) ? mp : true);
          sp = v ? sp : 0.f;
          float e = __expf(sp);
          Z += e;
          float c0 = v ? e * wpos[p] : 0.f;
          float c1 = v ? e * wpos[32 + p] : 0.f;
          g0[0] = fmaf(c0, xv0, g0[0]);
          g0[1] = fmaf(c0, xv1, g0[1]);
          g0[2] = fmaf(c0, xv2, g0[2]);
          g0[3] = fmaf(c0, xv3, g0[3]);
          g1[0] = fmaf(c1, xv0, g1[0]);
          g1[1] = fmaf(c1, xv1, g1[1]);
          g1[2] = fmaf(c1, xv2, g1[2]);
          g1[3] = fmaf(c1, xv3, g1[3]);
        }
      } else {
        Z += 5.f;
      }
    }
    float rZ = 1.f / Z;

    uint2 w0, w1;
    w0.x = pack2bf(g0[0] * rZ, g0[1] * rZ);
    w0.y = pack2bf(g0[2] * rZ, g0[3] * rZ);
    w1.x = pack2bf(g1[0] * rZ, g1[1] * rZ);
    w1.y = pack2bf(g1[2] * rZ, g1[3] * rZ);
    *(uint2*)&Gl[r][lr * 4] = w0;
    *(uint2*)&Gl[r][64 + lr * 4] = w1;
  }

  __syncthreads();

  // ----- Phase 2: out GEMM (wave = m-tile; validated fragment conventions) --
  {
    f4 acc0 = (f4)0.f, acc1 = (f4)0.f;
    #pragma unroll
    for (int ks = 0; ks < 4; ++ks) {
      bfrag b0 = *reinterpret_cast<const bfrag*>(&Gl[lr][ks * 32 + q * 8]);
      bfrag b1 = *reinterpret_cast<const bfrag*>(&Gl[16 + lr][ks * 32 + q * 8]);
      bfrag ah = *reinterpret_cast<const bfrag*>(
          WhiF + ((ks * 8 + wave) * 64 + lane) * 8);
      bfrag al = *reinterpret_cast<const bfrag*>(
          WloF + ((ks * 8 + wave) * 64 + lane) * 8);
      acc0 = __builtin_amdgcn_mfma_f32_16x16x32_bf16(ah, b0, acc0, 0, 0, 0);
      acc1 = __builtin_amdgcn_mfma_f32_16x16x32_bf16(ah, b1, acc1, 0, 0, 0);
      acc0 = __builtin_amdgcn_mfma_f32_16x16x32_bf16(al, b0, acc0, 0, 0, 0);
      acc1 = __builtin_amdgcn_mfma_f32_16x16x32_bf16(al, b1, acc1, 0, 0, 0);
    }
    int bb = pos0 >> 12;
    int hw0 = pos0 & 4095;
    float* op = out + (size_t)bb * (OC_ * HO_ * WO_) + hw0;
    #pragma unroll
    for (int rr = 0; rr < 4; ++rr) {
      int c = wave * 16 + q * 4 + rr;
      op[(size_t)c * 4096 + lr] = acc0[rr];
      op[(size_t)c * 4096 + 16 + lr] = acc1[rr];
    }
  }
}

// ---------------------------------------------------------------------------
extern "C" void kernel_launch(void* const* d_in, const int* in_sizes, int n_in,
                              void* d_out, int out_size, void* d_ws, size_t ws_size,
                              hipStream_t stream) {
  const float* x       = (const float*)d_in[0];
  const float* w_q     = (const float*)d_in[1];
  const float* w_k     = (const float*)d_in[2];
  const float* w_v     = (const float*)d_in[3];
  const float* row_emb = (const float*)d_in[4];
  const float* col_emb = (const float*)d_in[5];
  const float* mix_emb = (const float*)d_in[6];
  float* out = (float*)d_out;

  float* ws   = (float*)d_ws;
  u16*   xbt  = (u16*)(ws + XBT_OFF);
  u16*   MhiF = (u16*)(ws + MHI_OFF);
  u16*   MloF = (u16*)(ws + MLO_OFF);
  u16*   WhiF = (u16*)(ws + WHI_OFF);
  u16*   WloF = (u16*)(ws + WLO_OFF);
  float* wpos = ws + WPOS_OFF;

  mega_kernel<<<1024 + 33, 256, 0, stream>>>(x, xbt, w_q, w_k, w_v, row_emb,
                                             col_emb, mix_emb, MhiF, MloF,
                                             WhiF, WloF, wpos);
  attn_out_kernel<<<NPOS / 32, 512, 0, stream>>>(xbt, MhiF, MloF, wpos,
                                                 WhiF, WloF, out);
}

// Round 9
// 39.325 us; speedup vs baseline: 6.1242x; 1.0079x over previous
//
#include <hip/hip_runtime.h>

typedef unsigned int   uint_;
typedef unsigned short u16;

// Problem constants
#define B_    8
#define CIN_  64
#define H_    128
#define W_    128
#define OC_   128
#define HO_   64
#define WO_   64
#define NPOS  (B_ * HO_ * WO_)   // 32768

// ws layout (float offsets)
#define XBT_OFF  0          // bf16 x_bt (B,H,W,64) = 4194304 floats
#define MHI_OFF  4194304    // u16[4096]  = 2048 floats
#define MLO_OFF  4196352
#define WHI_OFF  4198400    // u16[16384] = 8192 floats
#define WLO_OFF  4206592
#define WPOS_OFF 4214784    // wpos0[25] @ +0, wpos1[25] @ +32

// ---------------------------------------------------------------------------
// helpers
// ---------------------------------------------------------------------------
__device__ __forceinline__ u16 f2bf(float x) {          // RNE float->bf16
  uint_ u = __float_as_uint(x);
  u += 0x7FFFu + ((u >> 16) & 1u);
  return (u16)(u >> 16);
}
__device__ __forceinline__ uint_ pack2bf(float lo, float hi) {
  return ((uint_)f2bf(hi) << 16) | (uint_)f2bf(lo);
}

template <int CTRL>
__device__ __forceinline__ float dpp_add(float x) {
  int y = __builtin_amdgcn_update_dpp(0, __float_as_int(x), CTRL, 0xf, 0xf, true);
  return x + __int_as_float(y);
}

typedef __attribute__((ext_vector_type(8))) short bfrag;
typedef __attribute__((ext_vector_type(4))) float f4;

// ---------------------------------------------------------------------------
// Dispatch 1 (mega): blocks 0..1023 = transpose x f32 -> xbt bf16;
// blocks 1024..1056 = prep (M-frags, wpos, Wv-frags).
// A-frag layout (16x16x32): lane=(i&15)+16*((k>>3)&3), reg=k&7.
// ---------------------------------------------------------------------------
__global__ __launch_bounds__(256) void mega_kernel(
    const float* __restrict__ x, u16* __restrict__ xbt,
    const float* __restrict__ w_q, const float* __restrict__ w_k,
    const float* __restrict__ w_v,
    const float* __restrict__ row_emb, const float* __restrict__ col_emb,
    const float* __restrict__ mix_emb,
    u16* __restrict__ MhiF, u16* __restrict__ MloF,
    u16* __restrict__ WhiF, u16* __restrict__ WloF,
    float* __restrict__ wpos) {
  if (blockIdx.x < 1024) {
    __shared__ float tile[64][129];
    int by = blockIdx.x;
    int b = by >> 7, y = by & 127;
    const float* xp = x + (size_t)b * (CIN_ * H_ * W_) + (size_t)y * W_;
    #pragma unroll
    for (int it = 0; it < 32; ++it) {
      int idx = threadIdx.x + it * 256;
      int c = idx >> 7, xw = idx & 127;
      tile[c][xw] = xp[(size_t)c * (H_ * W_) + xw];
    }
    __syncthreads();
    uint_* dst = (uint_*)(xbt + ((size_t)(b * H_ + y)) * (W_ * 64));
    #pragma unroll
    for (int it = 0; it < 16; ++it) {
      int idx = threadIdx.x + it * 256;   // = xw*32 + cp
      int xw = idx >> 5, cp = idx & 31;
      dst[idx] = pack2bf(tile[2 * cp][xw], tile[2 * cp + 1][xw]);
    }
  } else {
    int pb = blockIdx.x - 1024;   // 0..32
    if (pb < 16) {
      // M[a][c] = sum_o w_q[o,a] * w_k[o,c]  -> A-frag (i=c, k=a), 4 m-tiles
      int idx = pb * 256 + threadIdx.x;  // 0..4095
      int a = idx >> 6, c = idx & 63;
      float acc = 0.f;
      #pragma unroll 8
      for (int o = 0; o < 128; ++o)
        acc = fmaf(w_q[o * 64 + a], w_k[o * 64 + c], acc);
      u16 hi = f2bf(acc);
      float hif = __uint_as_float((uint_)hi << 16);
      u16 lo = f2bf(acc - hif);
      int m = c >> 4, lr = c & 15;
      int ks = a >> 5, q = (a >> 3) & 3, jr = a & 7;
      int off = ((ks * 4 + m) * 64 + (lr + 16 * q)) * 8 + jr;
      MhiF[off] = hi;
      MloF[off] = lo;
    } else if (pb == 16) {
      int p = threadIdx.x;
      if (p < 25) {
        int i = p / 5, j = p % 5;
        float a0 = 0.f, a1 = 0.f;
        for (int c = 0; c < 128; ++c) {
          float rc = row_emb[c * 5 + i] + col_emb[c * 5 + j];
          a0 = fmaf(rc, mix_emb[c * 2 + 0], a0);
          a1 = fmaf(rc, mix_emb[c * 2 + 1], a1);
        }
        float mx = fmaxf(a0, a1);
        float e0 = __expf(a0 - mx), e1 = __expf(a1 - mx);
        float inv = 1.f / (e0 + e1);
        wpos[p] = e0 * inv;
        wpos[32 + p] = e1 * inv;
      }
    } else {
      // Wv[c][k] = w_v[c*128+k]; A-frag (i=c, k), 8 m-tiles (c=128)
      int t = (pb - 17) * 256 + threadIdx.x;  // 0..4095
      #pragma unroll
      for (int e = 0; e < 4; ++e) {
        int elem = t * 4 + e;            // = c*128 + k
        int c = elem >> 7, k = elem & 127;
        float w = w_v[elem];
        u16 hi = f2bf(w);
        float hif = __uint_as_float((uint_)hi << 16);
        u16 lo = f2bf(w - hif);
        int m = c >> 4, lr = c & 15;
        int ks = k >> 5, q = (k >> 3) & 3, j = k & 7;
        int off = ((ks * 8 + m) * 64 + (lr + 16 * q)) * 8 + j;
        WhiF[off] = hi;
        WloF[off] = lo;
      }
    }
  }
}

// ---------------------------------------------------------------------------
// Dispatch 2 (fused stage + U + attn + out GEMM). 512 thr (8 waves) = 32 pos.
// XCD-swizzled blockIdx: each XCD owns one batch image (2.1 MB < 4 MB L2),
// streamed row-sequentially -> window reads are L2 hits after first touch.
// LDS: Xl [5][67][64] u16 = 42.9K + union(Ul f32[32][68] / Gl u16[32][136])
//      = 8.7K  -> 51.6 KB -> 3 blocks/CU (24 waves).
// Union safety: Ul fully written pre-barrier; in phase 1 wave w exclusively
// owns rows 4w..4w+3, reads its u before (in program order) writing Gl there;
// phase 2 reads Gl after the second barrier.
// grid = NPOS/32 = 1024.
// ---------------------------------------------------------------------------
__global__ __launch_bounds__(512) void attn_out_kernel(
    const u16* __restrict__ xbt, const u16* __restrict__ MhiF,
    const u16* __restrict__ MloF, const float* __restrict__ wpos,
    const u16* __restrict__ WhiF, const u16* __restrict__ WloF,
    float* __restrict__ out) {
  __shared__ u16 Xl[5 * 67 * 64];   // [row][col][ch], ch-stride 64 u16 = 128 B
  __shared__ union {
    float Ul[32][68];               // row stride 272 B
    u16   Gl[32][136];              // row stride 272 B
  } GU;

  int tid = threadIdx.x;
  int wave = tid >> 6, lane = tid & 63;
  int lr = lane & 15, q = lane >> 4;

  // XCD-aware bijective swizzle: XCD x gets blocks x*128..x*128+127
  // = one full batch image, positions streamed sequentially.
  int bid = (int)blockIdx.x;
  int swz = (bid & 7) * 128 + (bid >> 3);
  int pos0 = swz * 32;

  int b = pos0 >> 12;
  int ho0 = (pos0 >> 6) & 63;       // shared by all 32 positions
  int wo0 = pos0 & 63;              // 0 or 32
  int y0 = 2 * ho0, x0base = 2 * wo0;

  // ----- Stage x-window -> Xl (5 x 67 col-vectors of 64ch, clamped) -----
  {
    int sl = tid & 15;              // 8-byte ch-chunk within a col-vector
    int pi0 = tid >> 4;             // col-vector index step 32
    const u16* xbb = xbt + (size_t)b * (H_ * W_ * 64);
    #pragma unroll
    for (int it = 0; it < 11; ++it) {
      int pi = it * 32 + pi0;       // 0..351, need 0..334
      if (pi < 335) {
        int row = pi / 67;          // magic-mul
        int col = pi - row * 67;
        int yc = min(max(y0 + row - 2, 0), H_ - 1);
        int xc = min(max(x0base + col - 2, 0), W_ - 1);
        uint2 d = *(const uint2*)(xbb + ((size_t)yc * W_ + xc) * 64 + sl * 4);
        *(uint2*)(&Xl[pi * 64 + sl * 4]) = d;
      }
    }
  }

  // ----- Phase 0: U = M^T xq for the block's 32 positions (overlaps stage) --
  {
    int pt = wave >> 2, mm = wave & 3;      // pos-tile (0,1), m-tile (0..3)
    int pu = pos0 + pt * 16 + lr;           // B-frag col j = lr
    int bu = pu >> 12, hou = (pu >> 6) & 63, wou = pu & 63;
    const u16* xq = xbt + ((size_t)(bu * H_ + 2 * hou) * W_ + 2 * wou) * 64;
    f4 ua = (f4)0.f;
    #pragma unroll
    for (int ks = 0; ks < 2; ++ks) {
      bfrag bb = *reinterpret_cast<const bfrag*>(xq + ks * 32 + q * 8);
      bfrag ah = *reinterpret_cast<const bfrag*>(
          MhiF + ((ks * 4 + mm) * 64 + lane) * 8);
      bfrag al = *reinterpret_cast<const bfrag*>(
          MloF + ((ks * 4 + mm) * 64 + lane) * 8);
      ua = __builtin_amdgcn_mfma_f32_16x16x32_bf16(ah, bb, ua, 0, 0, 0);
      ua = __builtin_amdgcn_mfma_f32_16x16x32_bf16(al, bb, ua, 0, 0, 0);
    }
    #pragma unroll
    for (int r = 0; r < 4; ++r)
      GU.Ul[pt * 16 + lr][mm * 16 + q * 4 + r] = ua[r];
  }
  __syncthreads();

  // ----- Phase 1: attention from LDS -----
  {
    int r = wave * 4 + q;              // local position 0..31
    int wo = wo0 + r;
    const u16* xl0 = &Xl[(2 * r + 2) * 64 + lr * 4];  // (row0, col 2r+2, ch 4lr)

    f4 u = *reinterpret_cast<const f4*>(&GU.Ul[r][lr * 4]);
    bool mn = (wo > 0), mp = (wo < 63);

    float Z = 0.f;
    float g0[4] = {0.f, 0.f, 0.f, 0.f}, g1[4] = {0.f, 0.f, 0.f, 0.f};

    #pragma unroll
    for (int dy = -2; dy <= 2; ++dy) {
      int y = y0 + dy;
      if ((unsigned)y < (unsigned)H_) {   // block-uniform branch
        #pragma unroll
        for (int dx = -2; dx <= 2; ++dx) {
          const int p = (dy + 2) * 5 + (dx + 2);
          // base + compile-time element offset -> DS imm offset
          uint2 d = *(const uint2*)(xl0 + ((dy + 2) * 67 + dx) * 64);
          float xv0 = __uint_as_float(d.x << 16);
          float xv1 = __uint_as_float(d.x & 0xffff0000u);
          float xv2 = __uint_as_float(d.y << 16);
          float xv3 = __uint_as_float(d.y & 0xffff0000u);
          float sp = fmaf(u.x, xv0, fmaf(u.y, xv1, fmaf(u.z, xv2, u.w * xv3)));
          sp = dpp_add<0x121>(sp);   // row_ror:1
          sp = dpp_add<0x122>(sp);   // row_ror:2
          sp = dpp_add<0x124>(sp);   // row_ror:4
          sp = dpp_add<0x128>(sp);   // row_ror:8 -> full 64-ch sum per row
          bool v = (dx < 0) ? mn : ((dx == 2) ? mp : true);
          sp = v ? sp : 0.f;
          float e = __expf(sp);
          Z += e;
          float c0 = v ? e * wpos[p] : 0.f;
          float c1 = v ? e * wpos[32 + p] : 0.f;
          g0[0] = fmaf(c0, xv0, g0[0]);
          g0[1] = fmaf(c0, xv1, g0[1]);
          g0[2] = fmaf(c0, xv2, g0[2]);
          g0[3] = fmaf(c0, xv3, g0[3]);
          g1[0] = fmaf(c1, xv0, g1[0]);
          g1[1] = fmaf(c1, xv1, g1[1]);
          g1[2] = fmaf(c1, xv2, g1[2]);
          g1[3] = fmaf(c1, xv3, g1[3]);
        }
      } else {
        Z += 5.f;
      }
    }
    float rZ = 1.f / Z;

    uint2 w0, w1;
    w0.x = pack2bf(g0[0] * rZ, g0[1] * rZ);
    w0.y = pack2bf(g0[2] * rZ, g0[3] * rZ);
    w1.x = pack2bf(g1[0] * rZ, g1[1] * rZ);
    w1.y = pack2bf(g1[2] * rZ, g1[3] * rZ);
    *(uint2*)&GU.Gl[r][lr * 4] = w0;
    *(uint2*)&GU.Gl[r][64 + lr * 4] = w1;
  }

  __syncthreads();

  // ----- Phase 2: out GEMM (wave = m-tile; validated fragment conventions) --
  {
    f4 acc0 = (f4)0.f, acc1 = (f4)0.f;
    #pragma unroll
    for (int ks = 0; ks < 4; ++ks) {
      bfrag b0 = *reinterpret_cast<const bfrag*>(&GU.Gl[lr][ks * 32 + q * 8]);
      bfrag b1 = *reinterpret_cast<const bfrag*>(&GU.Gl[16 + lr][ks * 32 + q * 8]);
      bfrag ah = *reinterpret_cast<const bfrag*>(
          WhiF + ((ks * 8 + wave) * 64 + lane) * 8);
      bfrag al = *reinterpret_cast<const bfrag*>(
          WloF + ((ks * 8 + wave) * 64 + lane) * 8);
      acc0 = __builtin_amdgcn_mfma_f32_16x16x32_bf16(ah, b0, acc0, 0, 0, 0);
      acc1 = __builtin_amdgcn_mfma_f32_16x16x32_bf16(ah, b1, acc1, 0, 0, 0);
      acc0 = __builtin_amdgcn_mfma_f32_16x16x32_bf16(al, b0, acc0, 0, 0, 0);
      acc1 = __builtin_amdgcn_mfma_f32_16x16x32_bf16(al, b1, acc1, 0, 0, 0);
    }
    int bb = pos0 >> 12;
    int hw0 = pos0 & 4095;
    float* op = out + (size_t)bb * (OC_ * HO_ * WO_) + hw0;
    #pragma unroll
    for (int rr = 0; rr < 4; ++rr) {
      int c = wave * 16 + q * 4 + rr;
      op[(size_t)c * 4096 + lr] = acc0[rr];
      op[(size_t)c * 4096 + 16 + lr] = acc1[rr];
    }
  }
}

// ---------------------------------------------------------------------------
extern "C" void kernel_launch(void* const* d_in, const int* in_sizes, int n_in,
                              void* d_out, int out_size, void* d_ws, size_t ws_size,
                              hipStream_t stream) {
  const float* x       = (const float*)d_in[0];
  const float* w_q     = (const float*)d_in[1];
  const float* w_k     = (const float*)d_in[2];
  const float* w_v     = (const float*)d_in[3];
  const float* row_emb = (const float*)d_in[4];
  const float* col_emb = (const float*)d_in[5];
  const float* mix_emb = (const float*)d_in[6];
  float* out = (float*)d_out;

  float* ws   = (float*)d_ws;
  u16*   xbt  = (u16*)(ws + XBT_OFF);
  u16*   MhiF = (u16*)(ws + MHI_OFF);
  u16*   MloF = (u16*)(ws + MLO_OFF);
  u16*   WhiF = (u16*)(ws + WHI_OFF);
  u16*   WloF = (u16*)(ws + WLO_OFF);
  float* wpos = ws + WPOS_OFF;

  mega_kernel<<<1024 + 33, 256, 0, stream>>>(x, xbt, w_q, w_k, w_v, row_emb,
                                             col_emb, mix_emb, MhiF, MloF,
                                             WhiF, WloF, wpos);
  attn_out_kernel<<<NPOS / 32, 512, 0, stream>>>(xbt, MhiF, MloF, wpos,
                                                 WhiF, WloF, out);
}

// Round 11
// 36.916 us; speedup vs baseline: 6.5239x; 1.0653x over previous
//
#include <hip/hip_runtime.h>

typedef unsigned int   uint_;
typedef unsigned short u16;
typedef _Float16 f16;
typedef __attribute__((ext_vector_type(8))) _Float16 f16x8;  // MFMA A/B frag
typedef __attribute__((ext_vector_type(2))) _Float16 f16x2;
typedef __attribute__((ext_vector_type(2))) __fp16 fp16x2_builtin;
typedef __attribute__((ext_vector_type(4))) float f4;

// Problem constants
#define B_    8
#define CIN_  64
#define H_    128
#define W_    128
#define OC_   128
#define HO_   64
#define WO_   64
#define NPOS  (B_ * HO_ * WO_)   // 32768

// ws layout (float offsets)
#define XBT_OFF  0          // f16 x_bt (B,H,W,64) = 8388608 f16 = 4194304 floats
#define MF_OFF   4194304    // u16[4096]  (f16 M frags)
#define WF_OFF   4196352    // u16[16384] (f16 Wv frags)
#define WPOS_OFF 4204544    // wpos0[25] @ +0, wpos1[25] @ +32 (pre-scaled 2^-8)

// ---------------------------------------------------------------------------
// helpers
// ---------------------------------------------------------------------------
__device__ __forceinline__ uint_ h2u(f16x2 h) {
  union { uint_ u; f16x2 h; } c; c.h = h; return c.u;
}
__device__ __forceinline__ u16 f2h_bits(float x) {
  union { f16 h; u16 u; } c; c.h = (f16)x; return c.u;
}
__device__ __forceinline__ f16x2 cvt_pk2h(float lo, float hi) {
  union { fp16x2_builtin b; f16x2 h; } c;
  c.b = __builtin_amdgcn_cvt_pkrtz(lo, hi);
  return c.h;
}

template <int CTRL>
__device__ __forceinline__ float dpp_add(float x) {
  int y = __builtin_amdgcn_update_dpp(0, __float_as_int(x), CTRL, 0xf, 0xf, true);
  return x + __int_as_float(y);
}

__device__ __forceinline__ float fdot2h(f16x2 a, f16x2 b, float c) {
#if __has_builtin(__builtin_amdgcn_fdot2)
  return __builtin_amdgcn_fdot2(a, b, c, false);
#else
  return fmaf((float)a[0], (float)b[0], fmaf((float)a[1], (float)b[1], c));
#endif
}

// ---------------------------------------------------------------------------
// Dispatch 1 (mega): blocks 0..1023 = transpose x f32 -> xbt f16;
// blocks 1024..1056 = prep (M frags f16, wpos (x 2^-8), Wv frags f16).
// A-frag layout (16x16x32): lane=(i&15)+16*((k>>3)&3), reg=k&7.
// ---------------------------------------------------------------------------
__global__ __launch_bounds__(256) void mega_kernel(
    const float* __restrict__ x, u16* __restrict__ xbt,
    const float* __restrict__ w_q, const float* __restrict__ w_k,
    const float* __restrict__ w_v,
    const float* __restrict__ row_emb, const float* __restrict__ col_emb,
    const float* __restrict__ mix_emb,
    u16* __restrict__ MF, u16* __restrict__ WF, float* __restrict__ wpos) {
  if (blockIdx.x < 1024) {
    __shared__ float tile[64][129];
    int by = blockIdx.x;
    int b = by >> 7, y = by & 127;
    const float* xp = x + (size_t)b * (CIN_ * H_ * W_) + (size_t)y * W_;
    #pragma unroll
    for (int it = 0; it < 32; ++it) {
      int idx = threadIdx.x + it * 256;
      int c = idx >> 7, xw = idx & 127;
      tile[c][xw] = xp[(size_t)c * (H_ * W_) + xw];
    }
    __syncthreads();
    uint_* dst = (uint_*)(xbt + ((size_t)(b * H_ + y)) * (W_ * 64));
    #pragma unroll
    for (int it = 0; it < 16; ++it) {
      int idx = threadIdx.x + it * 256;   // = xw*32 + cp
      int xw = idx >> 5, cp = idx & 31;
      dst[idx] = h2u(cvt_pk2h(tile[2 * cp][xw], tile[2 * cp + 1][xw]));
    }
  } else {
    int pb = blockIdx.x - 1024;   // 0..32
    if (pb < 16) {
      // M[a][c] = sum_o w_q[o,a] * w_k[o,c]  -> A-frag (i=c, k=a), 4 m-tiles
      int idx = pb * 256 + threadIdx.x;  // 0..4095
      int a = idx >> 6, c = idx & 63;
      float acc = 0.f;
      #pragma unroll 8
      for (int o = 0; o < 128; ++o)
        acc = fmaf(w_q[o * 64 + a], w_k[o * 64 + c], acc);
      int m = c >> 4, lr = c & 15;
      int ks = a >> 5, q = (a >> 3) & 3, jr = a & 7;
      int off = ((ks * 4 + m) * 64 + (lr + 16 * q)) * 8 + jr;
      MF[off] = f2h_bits(acc);
    } else if (pb == 16) {
      int p = threadIdx.x;
      if (p < 25) {
        int i = p / 5, j = p % 5;
        float a0 = 0.f, a1 = 0.f;
        for (int c = 0; c < 128; ++c) {
          float rc = row_emb[c * 5 + i] + col_emb[c * 5 + j];
          a0 = fmaf(rc, mix_emb[c * 2 + 0], a0);
          a1 = fmaf(rc, mix_emb[c * 2 + 1], a1);
        }
        float mx = fmaxf(a0, a1);
        float e0 = __expf(a0 - mx), e1 = __expf(a1 - mx);
        float inv = 0.00390625f / (e0 + e1);   // softmax * 2^-8 (f16 headroom)
        wpos[p] = e0 * inv;
        wpos[32 + p] = e1 * inv;
      }
    } else {
      // Wv[c][k] = w_v[c*128+k]; A-frag (i=c, k), 8 m-tiles (c=128)
      int t = (pb - 17) * 256 + threadIdx.x;  // 0..4095
      #pragma unroll
      for (int e = 0; e < 4; ++e) {
        int elem = t * 4 + e;            // = c*128 + k
        int c = elem >> 7, k = elem & 127;
        int m = c >> 4, lr = c & 15;
        int ks = k >> 5, q = (k >> 3) & 3, j = k & 7;
        int off = ((ks * 8 + m) * 64 + (lr + 16 * q)) * 8 + j;
        WF[off] = f2h_bits(w_v[elem]);
      }
    }
  }
}

// ---------------------------------------------------------------------------
// Dispatch 2 (fused stage + U + attn + out GEMM). 512 thr (8 waves) = 32 pos.
// Zero-padded Xl staging -> branch/mask-free 25-tap loop: per tap
// 1 ds_read_b64 + 2 v_dot2_f32_f16 + 4 DPP + exp + 2 mul + 2 cvt_pk +
// 4 v_pk_fma_f16. PV accumulates packed f16 (coefs pre-scaled 2^-8 via wpos;
// rescale by 256/Z at the end -- softmax-invariant).
// LDS: Xl [5][67][68] u16 (pad: tap reads conflict-free) + union(Ul/Gl) 8.5K.
// grid = NPOS/32 = 1024, XCD-swizzled.
// ---------------------------------------------------------------------------
__global__ __launch_bounds__(512) void attn_out_kernel(
    const u16* __restrict__ xbt, const u16* __restrict__ MF,
    const float* __restrict__ wpos, const u16* __restrict__ WF,
    float* __restrict__ out) {
  __shared__ u16 Xl[5 * 67 * 68];   // [row][col][ch], ch-stride 68 u16 = 136 B
  __shared__ union {
    float Ul[32][68];               // row stride 272 B
    u16   Gl[32][136];
  } GU;

  int tid = threadIdx.x;
  int wave = tid >> 6, lane = tid & 63;
  int lr = lane & 15, q = lane >> 4;

  // XCD-aware bijective swizzle: XCD x owns one batch image (2.1 MB < L2)
  int bid = (int)blockIdx.x;
  int swz = (bid & 7) * 128 + (bid >> 3);
  int pos0 = swz * 32;

  int b = pos0 >> 12;
  int ho0 = (pos0 >> 6) & 63;
  int wo0 = pos0 & 63;              // 0 or 32
  int y0 = 2 * ho0, x0base = 2 * wo0;

  // ----- Stage x-window -> Xl, ZERO for OOB (handles all padding) -----
  {
    int sl = tid & 15;              // 8-byte ch-chunk within a col-vector
    int pi0 = tid >> 4;
    const u16* xbb = xbt + (size_t)b * (H_ * W_ * 64);
    #pragma unroll
    for (int it = 0; it < 11; ++it) {
      int pi = it * 32 + pi0;       // 0..351, need 0..334
      if (pi < 335) {
        int row = pi / 67;
        int col = pi - row * 67;
        int yr = y0 + row - 2, xr = x0base + col - 2;
        bool oob = ((unsigned)yr >= (unsigned)H_) | ((unsigned)xr >= (unsigned)W_);
        int yc = min(max(yr, 0), H_ - 1);
        int xc = min(max(xr, 0), W_ - 1);
        uint2 d = *(const uint2*)(xbb + ((size_t)yc * W_ + xc) * 64 + sl * 4);
        if (oob) { d.x = 0u; d.y = 0u; }
        *(uint2*)(&Xl[pi * 68 + sl * 4]) = d;
      }
    }
  }

  // ----- Phase 0: U = M^T xq (f16 M, single precision) -----
  {
    int pt = wave >> 2, mm = wave & 3;      // pos-tile (0,1), m-tile (0..3)
    int pu = pos0 + pt * 16 + lr;
    int bu = pu >> 12, hou = (pu >> 6) & 63, wou = pu & 63;
    const u16* xq = xbt + ((size_t)(bu * H_ + 2 * hou) * W_ + 2 * wou) * 64;
    f4 ua = (f4)0.f;
    #pragma unroll
    for (int ks = 0; ks < 2; ++ks) {
      f16x8 bb = *reinterpret_cast<const f16x8*>(xq + ks * 32 + q * 8);
      f16x8 ah = *reinterpret_cast<const f16x8*>(
          MF + ((ks * 4 + mm) * 64 + lane) * 8);
      ua = __builtin_amdgcn_mfma_f32_16x16x32_f16(ah, bb, ua, 0, 0, 0);
    }
    #pragma unroll
    for (int r = 0; r < 4; ++r)
      GU.Ul[pt * 16 + lr][mm * 16 + q * 4 + r] = ua[r];
  }
  __syncthreads();

  // ----- Phase 1: attention, branch-free 25-tap loop -----
  {
    int r = wave * 4 + q;              // local position 0..31
    const u16* xl0 = &Xl[(2 * r) * 68 + lr * 4];  // leftmost tap col base

    f4 u = *reinterpret_cast<const f4*>(&GU.Ul[r][lr * 4]);
    f16x2 u01 = cvt_pk2h(u.x, u.y);
    f16x2 u23 = cvt_pk2h(u.z, u.w);

    float Z = 0.f;
    f16x2 g0a = (f16x2)0.f, g0b = (f16x2)0.f;
    f16x2 g1a = (f16x2)0.f, g1b = (f16x2)0.f;

    #pragma unroll
    for (int p = 0; p < 25; ++p) {
      const int dy = p / 5, dx = p % 5;
      uint2 d = *(const uint2*)(xl0 + (dy * 67 + dx) * 68);
      f16x2 x01, x23;
      *(uint_*)&x01 = d.x;
      *(uint_*)&x23 = d.y;
      float sp = fdot2h(x23, u23, fdot2h(x01, u01, 0.f));
      sp = dpp_add<0x121>(sp);   // row_ror:1
      sp = dpp_add<0x122>(sp);   // row_ror:2
      sp = dpp_add<0x124>(sp);   // row_ror:4
      sp = dpp_add<0x128>(sp);   // row_ror:8 -> full 64-ch sum per row
      float e = __expf(sp);      // OOB taps: sp=0 -> e=1, PV adds 0
      Z += e;
      f16x2 c0 = cvt_pk2h(e * wpos[p], e * wpos[p]);
      f16x2 c1 = cvt_pk2h(e * wpos[32 + p], e * wpos[32 + p]);
      g0a = x01 * c0 + g0a;
      g0b = x23 * c0 + g0b;
      g1a = x01 * c1 + g1a;
      g1b = x23 * c1 + g1b;
    }
    float rZ = 256.f / Z;              // undo the 2^-8 wpos pre-scale
    f16x2 rZpk = cvt_pk2h(rZ, rZ);

    uint2 w0, w1;
    w0.x = h2u(g0a * rZpk); w0.y = h2u(g0b * rZpk);
    w1.x = h2u(g1a * rZpk); w1.y = h2u(g1b * rZpk);
    *(uint2*)&GU.Gl[r][lr * 4] = w0;
    *(uint2*)&GU.Gl[r][64 + lr * 4] = w1;
  }

  __syncthreads();

  // ----- Phase 2: out GEMM (f16 Wv frags, single precision) -----
  {
    f4 acc0 = (f4)0.f, acc1 = (f4)0.f;
    #pragma unroll
    for (int ks = 0; ks < 4; ++ks) {
      f16x8 b0 = *reinterpret_cast<const f16x8*>(&GU.Gl[lr][ks * 32 + q * 8]);
      f16x8 b1 = *reinterpret_cast<const f16x8*>(&GU.Gl[16 + lr][ks * 32 + q * 8]);
      f16x8 ah = *reinterpret_cast<const f16x8*>(
          WF + ((ks * 8 + wave) * 64 + lane) * 8);
      acc0 = __builtin_amdgcn_mfma_f32_16x16x32_f16(ah, b0, acc0, 0, 0, 0);
      acc1 = __builtin_amdgcn_mfma_f32_16x16x32_f16(ah, b1, acc1, 0, 0, 0);
    }
    int bb = pos0 >> 12;
    int hw0 = pos0 & 4095;
    float* op = out + (size_t)bb * (OC_ * HO_ * WO_) + hw0;
    #pragma unroll
    for (int rr = 0; rr < 4; ++rr) {
      int c = wave * 16 + q * 4 + rr;
      op[(size_t)c * 4096 + lr] = acc0[rr];
      op[(size_t)c * 4096 + 16 + lr] = acc1[rr];
    }
  }
}

// ---------------------------------------------------------------------------
extern "C" void kernel_launch(void* const* d_in, const int* in_sizes, int n_in,
                              void* d_out, int out_size, void* d_ws, size_t ws_size,
                              hipStream_t stream) {
  const float* x       = (const float*)d_in[0];
  const float* w_q     = (const float*)d_in[1];
  const float* w_k     = (const float*)d_in[2];
  const float* w_v     = (const float*)d_in[3];
  const float* row_emb = (const float*)d_in[4];
  const float* col_emb = (const float*)d_in[5];
  const float* mix_emb = (const float*)d_in[6];
  float* out = (float*)d_out;

  float* ws   = (float*)d_ws;
  u16*   xbt  = (u16*)(ws + XBT_OFF);
  u16*   MF   = (u16*)(ws + MF_OFF);
  u16*   WF   = (u16*)(ws + WF_OFF);
  float* wpos = ws + WPOS_OFF;

  mega_kernel<<<1024 + 33, 256, 0, stream>>>(x, xbt, w_q, w_k, w_v, row_emb,
                                             col_emb, mix_emb, MF, WF, wpos);
  attn_out_kernel<<<NPOS / 32, 512, 0, stream>>>(xbt, MF, wpos, WF, out);
}